// Round 18
// baseline (190.147 us; speedup 1.0000x reference)
//
#include <hip/hip_runtime.h>

typedef unsigned long long u64;
typedef unsigned long long u64x2 __attribute__((ext_vector_type(2)));

// ---------------- K1a: partial rank counts (no atomics) ----------------
__global__ __launch_bounds__(256)
void k_rank_part(const float* __restrict__ preds, int n, int cpb,
                 int* __restrict__ pc) {
  __shared__ float cs[1024];
  int c0 = blockIdx.y * cpb;
  int cn = min(cpb, n - c0);
  for (int j = threadIdx.x; j < cn; j += blockDim.x)
    cs[j] = preds[(c0 + j) * 5 + 4];
  __syncthreads();
  int i = blockIdx.x * blockDim.x + threadIdx.x;
  if (i >= n) return;
  float ci = preds[i * 5 + 4];
  int cnt = 0;
  const float4* cs4 = (const float4*)cs;
  int cn4 = cn >> 2;
  for (int j4 = 0; j4 < cn4; ++j4) {
    float4 c4 = cs4[j4];
    int jb = c0 + j4 * 4;
    cnt += (c4.x > ci) || (c4.x == ci && (jb + 0) < i);
    cnt += (c4.y > ci) || (c4.y == ci && (jb + 1) < i);
    cnt += (c4.z > ci) || (c4.z == ci && (jb + 2) < i);
    cnt += (c4.w > ci) || (c4.w == ci && (jb + 3) < i);
  }
  for (int j = cn4 * 4; j < cn; ++j)
    cnt += (cs[j] > ci) || (cs[j] == ci && (c0 + j) < i);
  pc[(size_t)blockIdx.y * n + i] = cnt;
}

// ---------------- K1b: sum partials + scatter ----------------
__global__ __launch_bounds__(256)
void k_scatter(const float* __restrict__ preds, const int* __restrict__ pc,
               int n, int nyb, float* __restrict__ sboxes,
               int* __restrict__ sidx) {
  int i = blockIdx.x * blockDim.x + threadIdx.x;
  if (i >= n) return;
  int pos = 0;
  for (int y = 0; y < nyb; ++y) pos += pc[(size_t)y * n + i];
  sboxes[pos * 4 + 0] = preds[i * 5 + 0];
  sboxes[pos * 4 + 1] = preds[i * 5 + 1];
  sboxes[pos * 4 + 2] = preds[i * 5 + 2];
  sboxes[pos * 4 + 3] = preds[i * 5 + 3];
  sidx[pos] = i;
}

// ---------------- K2: suppression bitmask ----------------
// M[row*nw + w] row-major (upper triangle; sub-diagonal garbage harmless).
// D1[row] = M[row][row>>6] (diagonal word).
// NONTEMPORAL stores: stream past L2 so k_scan's reads hit clean L3 lines
// instead of snooping dirty remote-XCD L2 lines.
__global__ void k_mask(const float* __restrict__ sboxes, int n,
                       const float* __restrict__ thr_p,
                       u64* __restrict__ M, u64* __restrict__ D1, int nw) {
  int wx = blockIdx.x;  // column word
  int ry = blockIdx.y;  // row group
  if (wx < ry) return;
  int lane = threadIdx.x;

  __shared__ float4 cb[64];
  __shared__ float cbar[64];
  const float4* sb4 = (const float4*)sboxes;
  int col0 = wx * 64;
  int cj = col0 + lane;
  int cjc = cj < n ? cj : n - 1;
  {
    float4 b4 = sb4[cjc];
    cb[lane] = b4;
    cbar[lane] = __fmul_rn(__fsub_rn(b4.z, b4.x), __fsub_rn(b4.w, b4.y));
  }
  __syncthreads();

  int row = ry * 64 + lane;
  if (row >= n) return;
  float th = *thr_p;
  float4 r4 = sb4[row];
  float rarea = __fmul_rn(__fsub_rn(r4.z, r4.x), __fsub_rn(r4.w, r4.y));

  u64 w = 0;
#pragma unroll 8
  for (int j = 0; j < 64; ++j) {
    float4 c4 = cb[j];
    float ix1 = fmaxf(r4.x, c4.x);
    float iy1 = fmaxf(r4.y, c4.y);
    float ix2 = fminf(r4.z, c4.z);
    float iy2 = fminf(r4.w, c4.w);
    float iw = fmaxf(__fsub_rn(ix2, ix1), 0.0f);
    float ih = fmaxf(__fsub_rn(iy2, iy1), 0.0f);
    float inter = __fmul_rn(iw, ih);
    float denom = __fadd_rn(__fsub_rn(__fadd_rn(rarea, cbar[j]), inter), 1e-12f);
    float iou = __fdiv_rn(inter, denom);
    int col = col0 + j;
    bool sup = (col > row) && (col < n) && (iou > th);
    w |= ((u64)sup) << j;
  }
  __builtin_nontemporal_store(w, &M[(size_t)row * nw + wx]);
  if (wx == ry) __builtin_nontemporal_store(w, &D1[row]);
}

// wave-uniform 64-bit broadcast from SGPR lane index b (single v_readlane pair)
__device__ __forceinline__ u64 bcast64(u64 v, int b) {
  unsigned lo = __builtin_amdgcn_readlane((unsigned)v, b);
  unsigned hi = __builtin_amdgcn_readlane((unsigned)(v >> 32), b);
  return ((u64)hi << 32) | lo;
}

// force a wave-uniform 64-bit value into scalar registers
__device__ __forceinline__ u64 sgpr64(u64 v) {
  unsigned lo = __builtin_amdgcn_readfirstlane((unsigned)v);
  unsigned hi = __builtin_amdgcn_readfirstlane((unsigned)(v >> 32));
  return ((u64)hi << 32) | lo;
}

// extract next pick row (uniform); when exhausted, clamp to chunk base row
#define EXTR1(RV, KX, c)                                                   \
  int RV = (c) * 64 + (KX ? (int)__builtin_ctzll(KX) : 0);                 \
  KX = KX ? (KX & (KX - 1)) : 0;

// issue 16 unconditional NONTEMPORAL row loads into v##P##0..15
#define ISSUE16(P, c)                                                      \
  {                                                                        \
    EXTR1(x0_, kx_, c)  EXTR1(x1_, kx_, c)  EXTR1(x2_, kx_, c)             \
    EXTR1(x3_, kx_, c)  EXTR1(x4_, kx_, c)  EXTR1(x5_, kx_, c)             \
    EXTR1(x6_, kx_, c)  EXTR1(x7_, kx_, c)  EXTR1(x8_, kx_, c)             \
    EXTR1(x9_, kx_, c)  EXTR1(xA_, kx_, c)  EXTR1(xB_, kx_, c)             \
    EXTR1(xC_, kx_, c)  EXTR1(xD_, kx_, c)  EXTR1(xE_, kx_, c)             \
    EXTR1(xF_, kx_, c)                                                     \
    v##P##0 = __builtin_nontemporal_load(Mv + (size_t)x0_ * nw2 + lane);   \
    v##P##1 = __builtin_nontemporal_load(Mv + (size_t)x1_ * nw2 + lane);   \
    v##P##2 = __builtin_nontemporal_load(Mv + (size_t)x2_ * nw2 + lane);   \
    v##P##3 = __builtin_nontemporal_load(Mv + (size_t)x3_ * nw2 + lane);   \
    v##P##4 = __builtin_nontemporal_load(Mv + (size_t)x4_ * nw2 + lane);   \
    v##P##5 = __builtin_nontemporal_load(Mv + (size_t)x5_ * nw2 + lane);   \
    v##P##6 = __builtin_nontemporal_load(Mv + (size_t)x6_ * nw2 + lane);   \
    v##P##7 = __builtin_nontemporal_load(Mv + (size_t)x7_ * nw2 + lane);   \
    v##P##8 = __builtin_nontemporal_load(Mv + (size_t)x8_ * nw2 + lane);   \
    v##P##9 = __builtin_nontemporal_load(Mv + (size_t)x9_ * nw2 + lane);   \
    v##P##10 = __builtin_nontemporal_load(Mv + (size_t)xA_ * nw2 + lane);  \
    v##P##11 = __builtin_nontemporal_load(Mv + (size_t)xB_ * nw2 + lane);  \
    v##P##12 = __builtin_nontemporal_load(Mv + (size_t)xC_ * nw2 + lane);  \
    v##P##13 = __builtin_nontemporal_load(Mv + (size_t)xD_ * nw2 + lane);  \
    v##P##14 = __builtin_nontemporal_load(Mv + (size_t)xE_ * nw2 + lane);  \
    v##P##15 = __builtin_nontemporal_load(Mv + (size_t)xF_ * nw2 + lane);  \
  }

// masked OR of 16 loaded rows into acc
#define CONSUME16(P, BASE)                                                 \
  acc0 |= ((BASE) + 0 < kc_) ? (v##P##0).x : 0;                            \
  acc1 |= ((BASE) + 0 < kc_) ? (v##P##0).y : 0;                            \
  acc0 |= ((BASE) + 1 < kc_) ? (v##P##1).x : 0;                            \
  acc1 |= ((BASE) + 1 < kc_) ? (v##P##1).y : 0;                            \
  acc0 |= ((BASE) + 2 < kc_) ? (v##P##2).x : 0;                            \
  acc1 |= ((BASE) + 2 < kc_) ? (v##P##2).y : 0;                            \
  acc0 |= ((BASE) + 3 < kc_) ? (v##P##3).x : 0;                            \
  acc1 |= ((BASE) + 3 < kc_) ? (v##P##3).y : 0;                            \
  acc0 |= ((BASE) + 4 < kc_) ? (v##P##4).x : 0;                            \
  acc1 |= ((BASE) + 4 < kc_) ? (v##P##4).y : 0;                            \
  acc0 |= ((BASE) + 5 < kc_) ? (v##P##5).x : 0;                            \
  acc1 |= ((BASE) + 5 < kc_) ? (v##P##5).y : 0;                            \
  acc0 |= ((BASE) + 6 < kc_) ? (v##P##6).x : 0;                            \
  acc1 |= ((BASE) + 6 < kc_) ? (v##P##6).y : 0;                            \
  acc0 |= ((BASE) + 7 < kc_) ? (v##P##7).x : 0;                            \
  acc1 |= ((BASE) + 7 < kc_) ? (v##P##7).y : 0;                            \
  acc0 |= ((BASE) + 8 < kc_) ? (v##P##8).x : 0;                            \
  acc1 |= ((BASE) + 8 < kc_) ? (v##P##8).y : 0;                            \
  acc0 |= ((BASE) + 9 < kc_) ? (v##P##9).x : 0;                            \
  acc1 |= ((BASE) + 9 < kc_) ? (v##P##9).y : 0;                            \
  acc0 |= ((BASE) + 10 < kc_) ? (v##P##10).x : 0;                          \
  acc1 |= ((BASE) + 10 < kc_) ? (v##P##10).y : 0;                          \
  acc0 |= ((BASE) + 11 < kc_) ? (v##P##11).x : 0;                          \
  acc1 |= ((BASE) + 11 < kc_) ? (v##P##11).y : 0;                          \
  acc0 |= ((BASE) + 12 < kc_) ? (v##P##12).x : 0;                          \
  acc1 |= ((BASE) + 12 < kc_) ? (v##P##12).y : 0;                          \
  acc0 |= ((BASE) + 13 < kc_) ? (v##P##13).x : 0;                          \
  acc1 |= ((BASE) + 13 < kc_) ? (v##P##13).y : 0;                          \
  acc0 |= ((BASE) + 14 < kc_) ? (v##P##14).x : 0;                          \
  acc1 |= ((BASE) + 14 < kc_) ? (v##P##14).y : 0;                          \
  acc0 |= ((BASE) + 15 < kc_) ? (v##P##15).x : 0;                          \
  acc1 |= ((BASE) + 15 < kc_) ? (v##P##15).y : 0;

// one 64-box chunk (scalar scan chain + batched-MLP apply + band prefetch)
#define CHUNK(c, BND)                                                      \
  if (out < maxp && (c) < nch) {                                           \
    u64 lw_ = ((c) & 1) ? live1 : live0;                                   \
    u64 rem_ = sgpr64(bcast64(lw_, (c) >> 1));                             \
    u64 K_ = 0;                                                            \
    int left_ = maxp - out, c2_ = 0;                                       \
    while (rem_) {                                                         \
      int b_ = __builtin_amdgcn_readfirstlane((int)__builtin_ctzll(rem_)); \
      K_ |= (u64)1 << b_;                                                  \
      ++c2_;                                                               \
      if (c2_ >= left_) break;                                             \
      u64 s_ = bcast64(BND, b_);                                           \
      rem_ &= rem_ - 1;                                                    \
      rem_ &= ~s_;                                                         \
    }                                                                      \
    int kc_ = (int)__popcll(K_);                                           \
    if ((K_ >> lane) & 1) {                                                \
      int pos_ = out + (int)__popcll(K_ & (((u64)1 << lane) - 1));         \
      if (pos_ < maxp) sel[pos_] = (c) * 64 + lane;                        \
    }                                                                      \
    out += kc_;                                                            \
    if (kc_ > 0 && out < maxp) {                                           \
      u64x2 vA0, vA1, vA2, vA3, vA4, vA5, vA6, vA7;                        \
      u64x2 vA8, vA9, vA10, vA11, vA12, vA13, vA14, vA15;                  \
      u64x2 vB0, vB1, vB2, vB3, vB4, vB5, vB6, vB7;                        \
      u64x2 vB8, vB9, vB10, vB11, vB12, vB13, vB14, vB15;                  \
      u64 acc0 = 0, acc1 = 0;                                              \
      u64 kx_ = K_;                                                        \
      ISSUE16(A, c)                                                        \
      ISSUE16(B, c)                                                        \
      CONSUME16(A, 0)                                                      \
      if (kc_ > 32) {                                                      \
        ISSUE16(A, c)                                                      \
        CONSUME16(B, 16)                                                   \
        ISSUE16(B, c)                                                      \
        CONSUME16(A, 32)                                                   \
        CONSUME16(B, 48)                                                   \
      } else {                                                             \
        CONSUME16(B, 16)                                                   \
      }                                                                    \
      live0 &= ~acc0;                                                      \
      live1 &= ~acc1;                                                      \
    }                                                                      \
    {                                                                      \
      int cc_ = (c) + 4;                                                   \
      if (cc_ < nch) BND = __builtin_nontemporal_load(D1 + (size_t)cc_ * 64 + lane); \
    }                                                                      \
  }

// ---------------- K3: single-wave greedy scan + fused emit ----------------
__global__ __launch_bounds__(64, 1)
void k_scan(const u64* __restrict__ M, const u64* __restrict__ D1,
            const float* __restrict__ preds, const int* __restrict__ sidx,
            int n, int nw, int maxp,
            int* __restrict__ sel, int* __restrict__ cnt,
            float* __restrict__ outp) {
  int lane = threadIdx.x;       // 0..63 (one wave)
  int nch = nw;                 // one 64-box word per chunk
  int nw2 = nw >> 1;
  const u64x2* Mv = (const u64x2*)M;

  // live words 2*lane and 2*lane+1
  u64 live0, live1;
  {
    int w0 = 2 * lane, w1 = 2 * lane + 1;
    u64 m0 = 0, m1 = 0;
    if (w0 < nw) {
      long long hi = (long long)(w0 + 1) * 64;
      m0 = (hi <= n) ? ~0ULL
                     : ((n > (long long)w0 * 64)
                            ? (((u64)1 << (n - w0 * 64)) - 1) : 0ULL);
    }
    if (w1 < nw) {
      long long hi = (long long)(w1 + 1) * 64;
      m1 = (hi <= n) ? ~0ULL
                     : ((n > (long long)w1 * 64)
                            ? (((u64)1 << (n - w1 * 64)) - 1) : 0ULL);
    }
    live0 = m0; live1 = m1;
  }

  // diag band ring (chunks c..c+3): lane holds D1[c*64+lane]
  u64 b0 = 0, b1 = 0, b2 = 0, b3 = 0;
  if (0 < nch) b0 = __builtin_nontemporal_load(D1 + (size_t)0 * 64 + lane);
  if (1 < nch) b1 = __builtin_nontemporal_load(D1 + (size_t)1 * 64 + lane);
  if (2 < nch) b2 = __builtin_nontemporal_load(D1 + (size_t)2 * 64 + lane);
  if (3 < nch) b3 = __builtin_nontemporal_load(D1 + (size_t)3 * 64 + lane);

  int out = 0;

  for (int kk = 0; kk < nch && out < maxp; kk += 4) {
    CHUNK(kk + 0, b0)
    CHUNK(kk + 1, b1)
    CHUNK(kk + 2, b2)
    CHUNK(kk + 3, b3)
  }

  // ---- fused emit (batched 3-level gather for MLP) ----
  {
    int nk = (out < maxp) ? out : maxp;
    if (lane == 0) *cnt = nk;
    int selv[16], origv[16];
#pragma unroll
    for (int t = 0; t < 16; ++t) {
      int k = lane + t * 64;
      selv[t] = (k < nk) ? sel[k] : -1;
    }
#pragma unroll
    for (int t = 0; t < 16; ++t)
      origv[t] = (selv[t] >= 0) ? sidx[selv[t]] : -1;
#pragma unroll
    for (int t = 0; t < 16; ++t) {
      int k = lane + t * 64;
      if (k < maxp) {
        int orig = origv[t];
        if (orig >= 0) {
          outp[k * 5 + 0] = preds[orig * 5 + 0];
          outp[k * 5 + 1] = preds[orig * 5 + 1];
          outp[k * 5 + 2] = preds[orig * 5 + 2];
          outp[k * 5 + 3] = preds[orig * 5 + 3];
          outp[k * 5 + 4] = preds[orig * 5 + 4];
          outp[(size_t)maxp * 5 + k] = (float)orig;
        } else {
          outp[k * 5 + 0] = 0.0f;
          outp[k * 5 + 1] = 0.0f;
          outp[k * 5 + 2] = 0.0f;
          outp[k * 5 + 3] = 0.0f;
          outp[k * 5 + 4] = 0.0f;
          outp[(size_t)maxp * 5 + k] = -1.0f;
        }
      }
    }
    // generic tail for maxp > 1024 (not taken at maxp=1000)
    for (int k = lane + 1024; k < maxp; k += 64) {
      if (k < nk) {
        int p = sel[k];
        int orig = sidx[p];
        for (int q = 0; q < 5; ++q) outp[k * 5 + q] = preds[orig * 5 + q];
        outp[(size_t)maxp * 5 + k] = (float)orig;
      } else {
        for (int q = 0; q < 5; ++q) outp[k * 5 + q] = 0.0f;
        outp[(size_t)maxp * 5 + k] = -1.0f;
      }
    }
  }
}

extern "C" void kernel_launch(void* const* d_in, const int* in_sizes, int n_in,
                              void* d_out, int out_size, void* d_ws, size_t ws_size,
                              hipStream_t stream) {
  const float* preds = (const float*)d_in[0];
  const float* thr   = (const float*)d_in[1];
  float* out = (float*)d_out;
  int n    = in_sizes[0] / 5;          // 8192
  int maxp = out_size / 6;             // 1000
  int nw   = (n + 63) / 64;            // 128
  int cpb  = 1024;
  int nyb  = (n + cpb - 1) / cpb;      // 8

  char* ws = (char*)d_ws;
  u64* M = (u64*)ws;
  size_t off = (size_t)n * nw * sizeof(u64);                   // 8 MB
  u64* D1 = (u64*)(ws + off);  off += (size_t)n * sizeof(u64); // 64 KB
  float* sboxes = (float*)(ws + off);  off += (size_t)n * 4 * sizeof(float);
  int*   sidx   = (int*)(ws + off);    off += (size_t)n * sizeof(int);
  int*   sel    = (int*)(ws + off);    off += (size_t)maxp * sizeof(int);
  int*   cnt    = (int*)(ws + off);    off += sizeof(int) * 4;
  int*   pc     = (int*)(ws + off);    // nyb * n ints

  hipLaunchKernelGGL(k_rank_part, dim3((n + 255) / 256, nyb), dim3(256), 0,
                     stream, preds, n, cpb, pc);
  hipLaunchKernelGGL(k_scatter, dim3((n + 255) / 256), dim3(256), 0, stream,
                     preds, pc, n, nyb, sboxes, sidx);
  hipLaunchKernelGGL(k_mask, dim3(nw, nw), dim3(64), 0, stream,
                     sboxes, n, thr, M, D1, nw);
  hipLaunchKernelGGL(k_scan, dim3(1), dim3(64), 0, stream,
                     M, D1, preds, sidx, n, nw, maxp, sel, cnt, out);
}

// Round 19
// 155.298 us; speedup vs baseline: 1.2244x; 1.2244x over previous
//
#include <hip/hip_runtime.h>

typedef unsigned long long u64;

#define FSLOTS 16   // per-row sparse column slots (avg set bits ~4)

// ---------------- K1a: partial rank counts (no atomics) ----------------
__global__ __launch_bounds__(256)
void k_rank_part(const float* __restrict__ preds, int n, int cpb,
                 int* __restrict__ pc) {
  __shared__ float cs[1024];
  int c0 = blockIdx.y * cpb;
  int cn = min(cpb, n - c0);
  for (int j = threadIdx.x; j < cn; j += blockDim.x)
    cs[j] = preds[(c0 + j) * 5 + 4];
  __syncthreads();
  int i = blockIdx.x * blockDim.x + threadIdx.x;
  if (i >= n) return;
  float ci = preds[i * 5 + 4];
  int cnt = 0;
  const float4* cs4 = (const float4*)cs;
  int cn4 = cn >> 2;
  for (int j4 = 0; j4 < cn4; ++j4) {
    float4 c4 = cs4[j4];
    int jb = c0 + j4 * 4;
    cnt += (c4.x > ci) || (c4.x == ci && (jb + 0) < i);
    cnt += (c4.y > ci) || (c4.y == ci && (jb + 1) < i);
    cnt += (c4.z > ci) || (c4.z == ci && (jb + 2) < i);
    cnt += (c4.w > ci) || (c4.w == ci && (jb + 3) < i);
  }
  for (int j = cn4 * 4; j < cn; ++j)
    cnt += (cs[j] > ci) || (cs[j] == ci && (c0 + j) < i);
  pc[(size_t)blockIdx.y * n + i] = cnt;
}

// ---------------- K1b: sum partials + scatter ----------------
__global__ __launch_bounds__(256)
void k_scatter(const float* __restrict__ preds, const int* __restrict__ pc,
               int n, int nyb, float* __restrict__ sboxes,
               int* __restrict__ sidx) {
  int i = blockIdx.x * blockDim.x + threadIdx.x;
  if (i >= n) return;
  int pos = 0;
  for (int y = 0; y < nyb; ++y) pos += pc[(size_t)y * n + i];
  sboxes[pos * 4 + 0] = preds[i * 5 + 0];
  sboxes[pos * 4 + 1] = preds[i * 5 + 1];
  sboxes[pos * 4 + 2] = preds[i * 5 + 2];
  sboxes[pos * 4 + 3] = preds[i * 5 + 3];
  sidx[pos] = i;
}

// ---------------- K2: suppression bitmask + SPARSE column lists ----------------
// M[row*nw + w] (full row, overflow fallback only). D1[row] = diag word.
// rowlist[row*FSLOTS + k] = k-th set column of row (col > row by construction,
// so lists are garbage-free). rowcnt[row] = total set bits (may exceed FSLOTS).
__global__ void k_mask(const float* __restrict__ sboxes, int n,
                       const float* __restrict__ thr_p,
                       u64* __restrict__ M, u64* __restrict__ D1,
                       int* __restrict__ rowcnt, int* __restrict__ rowlist,
                       int nw) {
  int wx = blockIdx.x;  // column word
  int ry = blockIdx.y;  // row group
  if (wx < ry) return;
  int lane = threadIdx.x;

  __shared__ float4 cb[64];
  __shared__ float cbar[64];
  const float4* sb4 = (const float4*)sboxes;
  int col0 = wx * 64;
  int cj = col0 + lane;
  int cjc = cj < n ? cj : n - 1;
  {
    float4 b4 = sb4[cjc];
    cb[lane] = b4;
    cbar[lane] = __fmul_rn(__fsub_rn(b4.z, b4.x), __fsub_rn(b4.w, b4.y));
  }
  __syncthreads();

  int row = ry * 64 + lane;
  if (row >= n) return;
  float th = *thr_p;
  float4 r4 = sb4[row];
  float rarea = __fmul_rn(__fsub_rn(r4.z, r4.x), __fsub_rn(r4.w, r4.y));

  u64 w = 0;
#pragma unroll 8
  for (int j = 0; j < 64; ++j) {
    float4 c4 = cb[j];
    float ix1 = fmaxf(r4.x, c4.x);
    float iy1 = fmaxf(r4.y, c4.y);
    float ix2 = fminf(r4.z, c4.z);
    float iy2 = fminf(r4.w, c4.w);
    float iw = fmaxf(__fsub_rn(ix2, ix1), 0.0f);
    float ih = fmaxf(__fsub_rn(iy2, iy1), 0.0f);
    float inter = __fmul_rn(iw, ih);
    float denom = __fadd_rn(__fsub_rn(__fadd_rn(rarea, cbar[j]), inter), 1e-12f);
    float iou = __fdiv_rn(inter, denom);
    int col = col0 + j;
    bool sup = (col > row) && (col < n) && (iou > th);
    w |= ((u64)sup) << j;
  }
  M[(size_t)row * nw + wx] = w;
  if (wx == ry) D1[row] = w;
  // sparse list build (avg ~0.03 bits per word -> loop almost always empty)
  u64 w2 = w;
  while (w2) {
    int j = (int)__builtin_ctzll(w2);
    w2 &= w2 - 1;
    int idx = atomicAdd(&rowcnt[row], 1);
    if (idx < FSLOTS) rowlist[(size_t)row * FSLOTS + idx] = col0 + j;
  }
}

// wave-uniform 64-bit broadcast from SGPR lane index b
__device__ __forceinline__ u64 bcast64(u64 v, int b) {
  unsigned lo = __builtin_amdgcn_readlane((unsigned)v, b);
  unsigned hi = __builtin_amdgcn_readlane((unsigned)(v >> 32), b);
  return ((u64)hi << 32) | lo;
}

// force a wave-uniform 64-bit value into scalar registers
__device__ __forceinline__ u64 sgpr64(u64 v) {
  unsigned lo = __builtin_amdgcn_readfirstlane((unsigned)v);
  unsigned hi = __builtin_amdgcn_readfirstlane((unsigned)(v >> 32));
  return ((u64)hi << 32) | lo;
}

#define APPLYJ(JV, T)                                                      \
  if ((T) < lim_) {                                                       \
    int j_ = (JV);                                                        \
    atomicAnd(&live[j_ >> 6], ~((u64)1 << (j_ & 63)));                    \
  }

// one 64-box chunk:
//  (a) prefetch all 64 lanes' rowcnt + list (hidden under the serial scan)
//  (b) serial register scan via diag band readlanes (scalar chain)
//  (c) sel write; picked lanes clear their row's listed bits via LDS atomicAnd
//  (d) overflow rows (>FSLOTS bits, ~never) AND the full M row cooperatively
//  (e) band prefetch c+4
#define CHUNK(c, BND)                                                      \
  if (out < maxp && (c) < nch) {                                           \
    int myrow_ = (c) * 64 + lane;                                          \
    int rowc_ = myrow_ < n ? myrow_ : n - 1;                               \
    int rc_ = rowcnt[rowc_];                                               \
    const int4* lp_ = (const int4*)(rowlist + (size_t)rowc_ * FSLOTS);     \
    int4 L0_ = lp_[0], L1_ = lp_[1], L2_ = lp_[2], L3_ = lp_[3];           \
    u64 rem_ = sgpr64(live[(c)]);                                          \
    u64 K_ = 0;                                                            \
    int left_ = maxp - out, c2_ = 0;                                       \
    while (rem_) {                                                         \
      int b_ = __builtin_amdgcn_readfirstlane((int)__builtin_ctzll(rem_)); \
      K_ |= (u64)1 << b_;                                                  \
      ++c2_;                                                               \
      if (c2_ >= left_) break;                                             \
      u64 s_ = bcast64(BND, b_);                                           \
      rem_ &= rem_ - 1;                                                    \
      rem_ &= ~s_;                                                         \
    }                                                                      \
    int kc_ = (int)__popcll(K_);                                           \
    bool mine_ = (K_ >> lane) & 1;                                         \
    if (mine_) {                                                           \
      int pos_ = out + (int)__popcll(K_ & (((u64)1 << lane) - 1));         \
      if (pos_ < maxp) sel[pos_] = myrow_;                                 \
    }                                                                      \
    out += kc_;                                                            \
    if (kc_ > 0 && out < maxp) {                                           \
      int lim_ = mine_ ? (rc_ < FSLOTS ? rc_ : FSLOTS) : 0;                \
      APPLYJ(L0_.x, 0)  APPLYJ(L0_.y, 1)  APPLYJ(L0_.z, 2)  APPLYJ(L0_.w, 3) \
      APPLYJ(L1_.x, 4)  APPLYJ(L1_.y, 5)  APPLYJ(L1_.z, 6)  APPLYJ(L1_.w, 7) \
      APPLYJ(L2_.x, 8)  APPLYJ(L2_.y, 9)  APPLYJ(L2_.z, 10) APPLYJ(L2_.w, 11) \
      APPLYJ(L3_.x, 12) APPLYJ(L3_.y, 13) APPLYJ(L3_.z, 14) APPLYJ(L3_.w, 15) \
      u64 ovf_ = __ballot(mine_ && rc_ > FSLOTS);                          \
      while (ovf_) {                                                       \
        int l_ = (int)__builtin_ctzll(ovf_);                               \
        ovf_ &= ovf_ - 1;                                                  \
        int r_ = (c) * 64 + l_;                                            \
        u64 v0_ = M[(size_t)r_ * nw + 2 * lane];                           \
        u64 v1_ = M[(size_t)r_ * nw + 2 * lane + 1];                       \
        live[2 * lane] &= ~v0_;                                            \
        live[2 * lane + 1] &= ~v1_;                                        \
      }                                                                    \
    }                                                                      \
    {                                                                      \
      int cc_ = (c) + 4;                                                   \
      if (cc_ < nch) BND = D1[(size_t)cc_ * 64 + lane];                    \
    }                                                                      \
  }

// ---------------- K3: single-wave greedy scan, SPARSE apply ----------------
__global__ __launch_bounds__(64, 1)
void k_scan(const u64* __restrict__ M, const u64* __restrict__ D1,
            const int* __restrict__ rowcnt, const int* __restrict__ rowlist,
            int n, int nw, int maxp,
            int* __restrict__ sel, int* __restrict__ cnt) {
  __shared__ u64 live[128];
  int lane = threadIdx.x;       // 0..63 (one wave)
  int nch = nw;                 // one 64-box word per chunk

  for (int w = lane; w < 128; w += 64) {
    u64 m = 0;
    if (w < nw) {
      long long hi = (long long)(w + 1) * 64;
      m = (hi <= n) ? ~0ULL
                    : ((n > (long long)w * 64)
                           ? (((u64)1 << (n - w * 64)) - 1) : 0ULL);
    }
    live[w] = m;
  }
  // single wave: LDS ops are in-order, no barrier needed

  // diag band ring (chunks c..c+3): lane holds D1[c*64+lane]
  u64 b0 = 0, b1 = 0, b2 = 0, b3 = 0;
  if (0 < nch) b0 = D1[(size_t)0 * 64 + lane];
  if (1 < nch) b1 = D1[(size_t)1 * 64 + lane];
  if (2 < nch) b2 = D1[(size_t)2 * 64 + lane];
  if (3 < nch) b3 = D1[(size_t)3 * 64 + lane];

  int out = 0;

  for (int kk = 0; kk < nch && out < maxp; kk += 4) {
    CHUNK(kk + 0, b0)
    CHUNK(kk + 1, b1)
    CHUNK(kk + 2, b2)
    CHUNK(kk + 3, b3)
  }
  if (lane == 0) *cnt = (out < maxp) ? out : maxp;
}

// ---------------- K4: gather outputs ----------------
__global__ void k_emit(const float* __restrict__ preds,
                       const int* __restrict__ sidx,
                       const int* __restrict__ sel,
                       const int* __restrict__ cnt,
                       int maxp, float* __restrict__ out) {
  int k = blockIdx.x * blockDim.x + threadIdx.x;
  if (k >= maxp) return;
  int nk = *cnt;
  if (k < nk) {
    int p = sel[k];
    int orig = sidx[p];
#pragma unroll
    for (int q = 0; q < 5; ++q) out[k * 5 + q] = preds[orig * 5 + q];
    out[(size_t)maxp * 5 + k] = (float)orig;
  } else {
#pragma unroll
    for (int q = 0; q < 5; ++q) out[k * 5 + q] = 0.0f;
    out[(size_t)maxp * 5 + k] = -1.0f;
  }
}

extern "C" void kernel_launch(void* const* d_in, const int* in_sizes, int n_in,
                              void* d_out, int out_size, void* d_ws, size_t ws_size,
                              hipStream_t stream) {
  const float* preds = (const float*)d_in[0];
  const float* thr   = (const float*)d_in[1];
  float* out = (float*)d_out;
  int n    = in_sizes[0] / 5;          // 8192
  int maxp = out_size / 6;             // 1000
  int nw   = (n + 63) / 64;            // 128
  int cpb  = 1024;
  int nyb  = (n + cpb - 1) / cpb;      // 8

  char* ws = (char*)d_ws;
  u64* M = (u64*)ws;
  size_t off = (size_t)n * nw * sizeof(u64);                   // 8 MB
  u64* D1 = (u64*)(ws + off);  off += (size_t)n * sizeof(u64); // 64 KB
  float* sboxes = (float*)(ws + off);  off += (size_t)n * 4 * sizeof(float);
  int*   sidx   = (int*)(ws + off);    off += (size_t)n * sizeof(int);
  int*   sel    = (int*)(ws + off);    off += (size_t)maxp * sizeof(int);
  int*   cnt    = (int*)(ws + off);    off += sizeof(int) * 4;
  int*   rowcnt = (int*)(ws + off);    off += (size_t)n * sizeof(int);
  int*   rowlist= (int*)(ws + off);    off += (size_t)n * FSLOTS * sizeof(int);
  int*   pc     = (int*)(ws + off);    // nyb * n ints

  hipMemsetAsync(rowcnt, 0, (size_t)n * sizeof(int), stream);

  hipLaunchKernelGGL(k_rank_part, dim3((n + 255) / 256, nyb), dim3(256), 0,
                     stream, preds, n, cpb, pc);
  hipLaunchKernelGGL(k_scatter, dim3((n + 255) / 256), dim3(256), 0, stream,
                     preds, pc, n, nyb, sboxes, sidx);
  hipLaunchKernelGGL(k_mask, dim3(nw, nw), dim3(64), 0, stream,
                     sboxes, n, thr, M, D1, rowcnt, rowlist, nw);
  hipLaunchKernelGGL(k_scan, dim3(1), dim3(64), 0, stream,
                     M, D1, rowcnt, rowlist, n, nw, maxp, sel, cnt);
  hipLaunchKernelGGL(k_emit, dim3((maxp + 255) / 256), dim3(256), 0, stream,
                     preds, sidx, sel, cnt, maxp, out);
}

// Round 20
// 105.207 us; speedup vs baseline: 1.8074x; 1.4761x over previous
//
#include <hip/hip_runtime.h>

typedef unsigned long long u64;

#define FSLOTS 16   // per-row sparse column slots (avg set bits ~4)

// ---------------- K1a: partial rank counts (no atomics) ----------------
__global__ __launch_bounds__(256)
void k_rank_part(const float* __restrict__ preds, int n, int cpb,
                 int* __restrict__ pc) {
  __shared__ float cs[1024];
  int c0 = blockIdx.y * cpb;
  int cn = min(cpb, n - c0);
  for (int j = threadIdx.x; j < cn; j += blockDim.x)
    cs[j] = preds[(c0 + j) * 5 + 4];
  __syncthreads();
  int i = blockIdx.x * blockDim.x + threadIdx.x;
  if (i >= n) return;
  float ci = preds[i * 5 + 4];
  int cnt = 0;
  const float4* cs4 = (const float4*)cs;
  int cn4 = cn >> 2;
  for (int j4 = 0; j4 < cn4; ++j4) {
    float4 c4 = cs4[j4];
    int jb = c0 + j4 * 4;
    cnt += (c4.x > ci) || (c4.x == ci && (jb + 0) < i);
    cnt += (c4.y > ci) || (c4.y == ci && (jb + 1) < i);
    cnt += (c4.z > ci) || (c4.z == ci && (jb + 2) < i);
    cnt += (c4.w > ci) || (c4.w == ci && (jb + 3) < i);
  }
  for (int j = cn4 * 4; j < cn; ++j)
    cnt += (cs[j] > ci) || (cs[j] == ci && (c0 + j) < i);
  pc[(size_t)blockIdx.y * n + i] = cnt;
}

// ---------------- K1b: sum partials + scatter ----------------
__global__ __launch_bounds__(256)
void k_scatter(const float* __restrict__ preds, const int* __restrict__ pc,
               int n, int nyb, float* __restrict__ sboxes,
               int* __restrict__ sidx) {
  int i = blockIdx.x * blockDim.x + threadIdx.x;
  if (i >= n) return;
  int pos = 0;
  for (int y = 0; y < nyb; ++y) pos += pc[(size_t)y * n + i];
  sboxes[pos * 4 + 0] = preds[i * 5 + 0];
  sboxes[pos * 4 + 1] = preds[i * 5 + 1];
  sboxes[pos * 4 + 2] = preds[i * 5 + 2];
  sboxes[pos * 4 + 3] = preds[i * 5 + 3];
  sidx[pos] = i;
}

// ---------------- K2: suppression bitmask + SPARSE column lists ----------------
__global__ void k_mask(const float* __restrict__ sboxes, int n,
                       const float* __restrict__ thr_p,
                       u64* __restrict__ M, u64* __restrict__ D1,
                       int* __restrict__ rowcnt, int* __restrict__ rowlist,
                       int nw) {
  int wx = blockIdx.x;  // column word
  int ry = blockIdx.y;  // row group
  if (wx < ry) return;
  int lane = threadIdx.x;

  __shared__ float4 cb[64];
  __shared__ float cbar[64];
  const float4* sb4 = (const float4*)sboxes;
  int col0 = wx * 64;
  int cj = col0 + lane;
  int cjc = cj < n ? cj : n - 1;
  {
    float4 b4 = sb4[cjc];
    cb[lane] = b4;
    cbar[lane] = __fmul_rn(__fsub_rn(b4.z, b4.x), __fsub_rn(b4.w, b4.y));
  }
  __syncthreads();

  int row = ry * 64 + lane;
  if (row >= n) return;
  float th = *thr_p;
  float4 r4 = sb4[row];
  float rarea = __fmul_rn(__fsub_rn(r4.z, r4.x), __fsub_rn(r4.w, r4.y));

  u64 w = 0;
#pragma unroll 8
  for (int j = 0; j < 64; ++j) {
    float4 c4 = cb[j];
    float ix1 = fmaxf(r4.x, c4.x);
    float iy1 = fmaxf(r4.y, c4.y);
    float ix2 = fminf(r4.z, c4.z);
    float iy2 = fminf(r4.w, c4.w);
    float iw = fmaxf(__fsub_rn(ix2, ix1), 0.0f);
    float ih = fmaxf(__fsub_rn(iy2, iy1), 0.0f);
    float inter = __fmul_rn(iw, ih);
    float denom = __fadd_rn(__fsub_rn(__fadd_rn(rarea, cbar[j]), inter), 1e-12f);
    float iou = __fdiv_rn(inter, denom);
    int col = col0 + j;
    bool sup = (col > row) && (col < n) && (iou > th);
    w |= ((u64)sup) << j;
  }
  M[(size_t)row * nw + wx] = w;
  if (wx == ry) D1[row] = w;
  u64 w2 = w;
  while (w2) {
    int j = (int)__builtin_ctzll(w2);
    w2 &= w2 - 1;
    int idx = atomicAdd(&rowcnt[row], 1);
    if (idx < FSLOTS) rowlist[(size_t)row * FSLOTS + idx] = col0 + j;
  }
}

// wave-uniform 64-bit broadcast from SGPR lane index b
__device__ __forceinline__ u64 bcast64(u64 v, int b) {
  unsigned lo = __builtin_amdgcn_readlane((unsigned)v, b);
  unsigned hi = __builtin_amdgcn_readlane((unsigned)(v >> 32), b);
  return ((u64)hi << 32) | lo;
}

// force a wave-uniform 64-bit value into scalar registers
__device__ __forceinline__ u64 sgpr64(u64 v) {
  unsigned lo = __builtin_amdgcn_readfirstlane((unsigned)v);
  unsigned hi = __builtin_amdgcn_readfirstlane((unsigned)(v >> 32));
  return ((u64)hi << 32) | lo;
}

// 64-lane OR butterfly (6 dependent shfl_xor steps)
__device__ __forceinline__ u64 wor64(u64 v) {
#pragma unroll
  for (int off = 32; off; off >>= 1)
    v |= __shfl_xor(v, off, 64);
  return v;
}

#define APPLYJ(JV, T)                                                      \
  if ((T) < lim_) {                                                        \
    int j_ = (JV);                                                         \
    atomicAnd(&live[j_ >> 6], ~((u64)1 << (j_ & 63)));                     \
  }

// one 64-box chunk: bulk keep-set via OR-butterflies (serial loop only over
// the ~1 intra-word "hot" bit), sel write, sparse LDS apply, ring prefetch.
#define CHUNK(c, BND, RC, LA, LB, LC, LD)                                  \
  if (out < maxp && (c) < nch) {                                           \
    u64 rem_ = sgpr64(live[(c)]);                                          \
    if (rem_) {                                                            \
      u64 K_;                                                              \
      u64 my_ = ((rem_ >> lane) & 1) ? (BND) : 0;                          \
      u64 A_ = sgpr64(wor64(my_));                                         \
      u64 hot_ = rem_ & A_;                                                \
      if (!hot_) {                                                         \
        K_ = rem_;                                                         \
      } else {                                                             \
        u64 defK_ = rem_ & ~A_;                                            \
        u64 myk_ = ((defK_ >> lane) & 1) ? (BND) : 0;                      \
        u64 S_ = sgpr64(wor64(myk_));                                      \
        K_ = defK_;                                                        \
        while (hot_) {                                                     \
          int b_ = __builtin_amdgcn_readfirstlane(                         \
              (int)__builtin_ctzll(hot_));                                 \
          hot_ &= hot_ - 1;                                                \
          if (!((S_ >> b_) & 1)) {                                         \
            K_ |= (u64)1 << b_;                                            \
            S_ |= bcast64(BND, b_);                                        \
          }                                                                \
        }                                                                  \
      }                                                                    \
      int kc_ = (int)__popcll(K_);                                         \
      bool mine_ = (K_ >> lane) & 1;                                       \
      if (mine_) {                                                         \
        int pos_ = out + (int)__popcll(K_ & (((u64)1 << lane) - 1));       \
        if (pos_ < maxp) sel[pos_] = (c) * 64 + lane;                      \
      }                                                                    \
      out += kc_;                                                          \
      if (kc_ > 0 && out < maxp) {                                         \
        int lim_ = mine_ ? ((RC) < FSLOTS ? (RC) : FSLOTS) : 0;            \
        APPLYJ((LA).x, 0)  APPLYJ((LA).y, 1)                               \
        APPLYJ((LA).z, 2)  APPLYJ((LA).w, 3)                               \
        APPLYJ((LB).x, 4)  APPLYJ((LB).y, 5)                               \
        APPLYJ((LB).z, 6)  APPLYJ((LB).w, 7)                               \
        APPLYJ((LC).x, 8)  APPLYJ((LC).y, 9)                               \
        APPLYJ((LC).z, 10) APPLYJ((LC).w, 11)                              \
        APPLYJ((LD).x, 12) APPLYJ((LD).y, 13)                              \
        APPLYJ((LD).z, 14) APPLYJ((LD).w, 15)                              \
        u64 ovf_ = __ballot(mine_ && (RC) > FSLOTS);                       \
        while (ovf_) {                                                     \
          int l_ = (int)__builtin_ctzll(ovf_);                             \
          ovf_ &= ovf_ - 1;                                                \
          int r_ = (c) * 64 + l_;                                          \
          u64 v0_ = M[(size_t)r_ * nw + 2 * lane];                         \
          u64 v1_ = M[(size_t)r_ * nw + 2 * lane + 1];                     \
          live[2 * lane] &= ~v0_;                                          \
          live[2 * lane + 1] &= ~v1_;                                      \
        }                                                                  \
      }                                                                    \
    }                                                                      \
    {                                                                      \
      int cc_ = (c) + 4;                                                   \
      if (cc_ < nch) {                                                     \
        int r_ = cc_ * 64 + lane;                                          \
        int rr_ = r_ < n ? r_ : n - 1;                                     \
        BND = D1[rr_];                                                     \
        RC = rowcnt[rr_];                                                  \
        const int4* lp_ = (const int4*)(rowlist + (size_t)rr_ * FSLOTS);   \
        LA = lp_[0]; LB = lp_[1]; LC = lp_[2]; LD = lp_[3];                \
      }                                                                    \
    }                                                                      \
  }

#define PREF(cc, BND, RC, LA, LB, LC, LD)                                  \
  if ((cc) < nch) {                                                        \
    int r_ = (cc) * 64 + lane;                                             \
    int rr_ = r_ < n ? r_ : n - 1;                                         \
    BND = D1[rr_];                                                         \
    RC = rowcnt[rr_];                                                      \
    const int4* lp_ = (const int4*)(rowlist + (size_t)rr_ * FSLOTS);       \
    LA = lp_[0]; LB = lp_[1]; LC = lp_[2]; LD = lp_[3];                    \
  }

// ---------------- K3: single-wave bulk greedy scan, sparse apply ----------------
__global__ __launch_bounds__(64, 1)
void k_scan(const u64* __restrict__ M, const u64* __restrict__ D1,
            const int* __restrict__ rowcnt, const int* __restrict__ rowlist,
            int n, int nw, int maxp,
            int* __restrict__ sel, int* __restrict__ cnt) {
  __shared__ u64 live[128];
  int lane = threadIdx.x;       // 0..63 (one wave)
  int nch = nw;                 // one 64-box word per chunk

  for (int w = lane; w < 128; w += 64) {
    u64 m = 0;
    if (w < nw) {
      long long hi = (long long)(w + 1) * 64;
      m = (hi <= n) ? ~0ULL
                    : ((n > (long long)w * 64)
                           ? (((u64)1 << (n - w * 64)) - 1) : 0ULL);
    }
    live[w] = m;
  }
  // single wave: LDS ops are in-order, no barrier needed

  // 4-deep ring: diag band + sparse row data for chunks c..c+3
  u64 b0 = 0, b1 = 0, b2 = 0, b3 = 0;
  int rc0 = 0, rc1 = 0, rc2 = 0, rc3 = 0;
  int4 l00 = {0,0,0,0}, l01 = {0,0,0,0}, l02 = {0,0,0,0}, l03 = {0,0,0,0};
  int4 l10 = {0,0,0,0}, l11 = {0,0,0,0}, l12 = {0,0,0,0}, l13 = {0,0,0,0};
  int4 l20 = {0,0,0,0}, l21 = {0,0,0,0}, l22 = {0,0,0,0}, l23 = {0,0,0,0};
  int4 l30 = {0,0,0,0}, l31 = {0,0,0,0}, l32 = {0,0,0,0}, l33 = {0,0,0,0};
  PREF(0, b0, rc0, l00, l01, l02, l03)
  PREF(1, b1, rc1, l10, l11, l12, l13)
  PREF(2, b2, rc2, l20, l21, l22, l23)
  PREF(3, b3, rc3, l30, l31, l32, l33)

  int out = 0;

  for (int kk = 0; kk < nch && out < maxp; kk += 4) {
    CHUNK(kk + 0, b0, rc0, l00, l01, l02, l03)
    CHUNK(kk + 1, b1, rc1, l10, l11, l12, l13)
    CHUNK(kk + 2, b2, rc2, l20, l21, l22, l23)
    CHUNK(kk + 3, b3, rc3, l30, l31, l32, l33)
  }
  if (lane == 0) *cnt = (out < maxp) ? out : maxp;
}

// ---------------- K4: gather outputs ----------------
__global__ void k_emit(const float* __restrict__ preds,
                       const int* __restrict__ sidx,
                       const int* __restrict__ sel,
                       const int* __restrict__ cnt,
                       int maxp, float* __restrict__ out) {
  int k = blockIdx.x * blockDim.x + threadIdx.x;
  if (k >= maxp) return;
  int nk = *cnt;
  if (k < nk) {
    int p = sel[k];
    int orig = sidx[p];
#pragma unroll
    for (int q = 0; q < 5; ++q) out[k * 5 + q] = preds[orig * 5 + q];
    out[(size_t)maxp * 5 + k] = (float)orig;
  } else {
#pragma unroll
    for (int q = 0; q < 5; ++q) out[k * 5 + q] = 0.0f;
    out[(size_t)maxp * 5 + k] = -1.0f;
  }
}

extern "C" void kernel_launch(void* const* d_in, const int* in_sizes, int n_in,
                              void* d_out, int out_size, void* d_ws, size_t ws_size,
                              hipStream_t stream) {
  const float* preds = (const float*)d_in[0];
  const float* thr   = (const float*)d_in[1];
  float* out = (float*)d_out;
  int n    = in_sizes[0] / 5;          // 8192
  int maxp = out_size / 6;             // 1000
  int nw   = (n + 63) / 64;            // 128
  int cpb  = 1024;
  int nyb  = (n + cpb - 1) / cpb;      // 8

  char* ws = (char*)d_ws;
  u64* M = (u64*)ws;
  size_t off = (size_t)n * nw * sizeof(u64);                   // 8 MB
  u64* D1 = (u64*)(ws + off);  off += (size_t)n * sizeof(u64); // 64 KB
  float* sboxes = (float*)(ws + off);  off += (size_t)n * 4 * sizeof(float);
  int*   sidx   = (int*)(ws + off);    off += (size_t)n * sizeof(int);
  int*   sel    = (int*)(ws + off);    off += (size_t)maxp * sizeof(int);
  int*   cnt    = (int*)(ws + off);    off += sizeof(int) * 4;
  int*   rowcnt = (int*)(ws + off);    off += (size_t)n * sizeof(int);
  int*   rowlist= (int*)(ws + off);    off += (size_t)n * FSLOTS * sizeof(int);
  int*   pc     = (int*)(ws + off);    // nyb * n ints

  hipMemsetAsync(rowcnt, 0, (size_t)n * sizeof(int), stream);

  hipLaunchKernelGGL(k_rank_part, dim3((n + 255) / 256, nyb), dim3(256), 0,
                     stream, preds, n, cpb, pc);
  hipLaunchKernelGGL(k_scatter, dim3((n + 255) / 256), dim3(256), 0, stream,
                     preds, pc, n, nyb, sboxes, sidx);
  hipLaunchKernelGGL(k_mask, dim3(nw, nw), dim3(64), 0, stream,
                     sboxes, n, thr, M, D1, rowcnt, rowlist, nw);
  hipLaunchKernelGGL(k_scan, dim3(1), dim3(64), 0, stream,
                     M, D1, rowcnt, rowlist, n, nw, maxp, sel, cnt);
  hipLaunchKernelGGL(k_emit, dim3((maxp + 255) / 256), dim3(256), 0, stream,
                     preds, sidx, sel, cnt, maxp, out);
}

// Round 21
// 99.086 us; speedup vs baseline: 1.9190x; 1.0618x over previous
//
#include <hip/hip_runtime.h>

typedef unsigned long long u64;

#define FSLOTS 16   // per-row sparse column slots (avg set bits ~4)

// ---------------- K1a: partial rank counts (no atomics) ----------------
__global__ __launch_bounds__(256)
void k_rank_part(const float* __restrict__ preds, int n, int cpb,
                 int* __restrict__ pc) {
  __shared__ float cs[1024];
  int c0 = blockIdx.y * cpb;
  int cn = min(cpb, n - c0);
  for (int j = threadIdx.x; j < cn; j += blockDim.x)
    cs[j] = preds[(c0 + j) * 5 + 4];
  __syncthreads();
  int i = blockIdx.x * blockDim.x + threadIdx.x;
  if (i >= n) return;
  float ci = preds[i * 5 + 4];
  int cnt = 0;
  const float4* cs4 = (const float4*)cs;
  int cn4 = cn >> 2;
  for (int j4 = 0; j4 < cn4; ++j4) {
    float4 c4 = cs4[j4];
    int jb = c0 + j4 * 4;
    cnt += (c4.x > ci) || (c4.x == ci && (jb + 0) < i);
    cnt += (c4.y > ci) || (c4.y == ci && (jb + 1) < i);
    cnt += (c4.z > ci) || (c4.z == ci && (jb + 2) < i);
    cnt += (c4.w > ci) || (c4.w == ci && (jb + 3) < i);
  }
  for (int j = cn4 * 4; j < cn; ++j)
    cnt += (cs[j] > ci) || (cs[j] == ci && (c0 + j) < i);
  pc[(size_t)blockIdx.y * n + i] = cnt;
}

// ---------------- K1b: sum partials + scatter (+ rowcnt zeroing) ----------------
__global__ __launch_bounds__(256)
void k_scatter(const float* __restrict__ preds, const int* __restrict__ pc,
               int n, int nyb, float* __restrict__ sboxes,
               int* __restrict__ sidx, int* __restrict__ rowcnt) {
  int i = blockIdx.x * blockDim.x + threadIdx.x;
  if (i >= n) return;
  rowcnt[i] = 0;   // replaces hipMemsetAsync (runtime fill kernel cost ~39us)
  int pos = 0;
  for (int y = 0; y < nyb; ++y) pos += pc[(size_t)y * n + i];
  sboxes[pos * 4 + 0] = preds[i * 5 + 0];
  sboxes[pos * 4 + 1] = preds[i * 5 + 1];
  sboxes[pos * 4 + 2] = preds[i * 5 + 2];
  sboxes[pos * 4 + 3] = preds[i * 5 + 3];
  sidx[pos] = i;
}

// ---------------- K2: suppression bitmask + SPARSE column lists ----------------
__global__ void k_mask(const float* __restrict__ sboxes, int n,
                       const float* __restrict__ thr_p,
                       u64* __restrict__ M, u64* __restrict__ D1,
                       int* __restrict__ rowcnt, int* __restrict__ rowlist,
                       int nw) {
  int wx = blockIdx.x;  // column word
  int ry = blockIdx.y;  // row group
  if (wx < ry) return;
  int lane = threadIdx.x;

  __shared__ float4 cb[64];
  __shared__ float cbar[64];
  const float4* sb4 = (const float4*)sboxes;
  int col0 = wx * 64;
  int cj = col0 + lane;
  int cjc = cj < n ? cj : n - 1;
  {
    float4 b4 = sb4[cjc];
    cb[lane] = b4;
    cbar[lane] = __fmul_rn(__fsub_rn(b4.z, b4.x), __fsub_rn(b4.w, b4.y));
  }
  __syncthreads();

  int row = ry * 64 + lane;
  if (row >= n) return;
  float th = *thr_p;
  float4 r4 = sb4[row];
  float rarea = __fmul_rn(__fsub_rn(r4.z, r4.x), __fsub_rn(r4.w, r4.y));

  u64 w = 0;
#pragma unroll 8
  for (int j = 0; j < 64; ++j) {
    float4 c4 = cb[j];
    float ix1 = fmaxf(r4.x, c4.x);
    float iy1 = fmaxf(r4.y, c4.y);
    float ix2 = fminf(r4.z, c4.z);
    float iy2 = fminf(r4.w, c4.w);
    float iw = fmaxf(__fsub_rn(ix2, ix1), 0.0f);
    float ih = fmaxf(__fsub_rn(iy2, iy1), 0.0f);
    float inter = __fmul_rn(iw, ih);
    float denom = __fadd_rn(__fsub_rn(__fadd_rn(rarea, cbar[j]), inter), 1e-12f);
    float iou = __fdiv_rn(inter, denom);
    int col = col0 + j;
    bool sup = (col > row) && (col < n) && (iou > th);
    w |= ((u64)sup) << j;
  }
  M[(size_t)row * nw + wx] = w;
  if (wx == ry) D1[row] = w;
  u64 w2 = w;
  while (w2) {
    int j = (int)__builtin_ctzll(w2);
    w2 &= w2 - 1;
    int idx = atomicAdd(&rowcnt[row], 1);
    if (idx < FSLOTS) rowlist[(size_t)row * FSLOTS + idx] = col0 + j;
  }
}

// wave-uniform 64-bit broadcast from SGPR lane index b
__device__ __forceinline__ u64 bcast64(u64 v, int b) {
  unsigned lo = __builtin_amdgcn_readlane((unsigned)v, b);
  unsigned hi = __builtin_amdgcn_readlane((unsigned)(v >> 32), b);
  return ((u64)hi << 32) | lo;
}

// force a wave-uniform 64-bit value into scalar registers
__device__ __forceinline__ u64 sgpr64(u64 v) {
  unsigned lo = __builtin_amdgcn_readfirstlane((unsigned)v);
  unsigned hi = __builtin_amdgcn_readfirstlane((unsigned)(v >> 32));
  return ((u64)hi << 32) | lo;
}

// 64-lane OR butterfly (6 dependent shfl_xor steps)
__device__ __forceinline__ u64 wor64(u64 v) {
#pragma unroll
  for (int off = 32; off; off >>= 1)
    v |= __shfl_xor(v, off, 64);
  return v;
}

#define APPLYJ(JV, T)                                                      \
  if ((T) < lim_) {                                                        \
    int j_ = (JV);                                                         \
    atomicAnd(&live[j_ >> 6], ~((u64)1 << (j_ & 63)));                     \
  }

// one 64-box chunk: bulk keep-set via OR-butterflies (serial loop only over
// the ~1 intra-word "hot" bit), sel write, sparse LDS apply, ring prefetch.
#define CHUNK(c, BND, RC, LA, LB, LC, LD)                                  \
  if (out < maxp && (c) < nch) {                                           \
    u64 rem_ = sgpr64(live[(c)]);                                          \
    if (rem_) {                                                            \
      u64 K_;                                                              \
      u64 my_ = ((rem_ >> lane) & 1) ? (BND) : 0;                          \
      u64 A_ = sgpr64(wor64(my_));                                         \
      u64 hot_ = rem_ & A_;                                                \
      if (!hot_) {                                                         \
        K_ = rem_;                                                         \
      } else {                                                             \
        u64 defK_ = rem_ & ~A_;                                            \
        u64 myk_ = ((defK_ >> lane) & 1) ? (BND) : 0;                      \
        u64 S_ = sgpr64(wor64(myk_));                                      \
        K_ = defK_;                                                        \
        while (hot_) {                                                     \
          int b_ = __builtin_amdgcn_readfirstlane(                         \
              (int)__builtin_ctzll(hot_));                                 \
          hot_ &= hot_ - 1;                                                \
          if (!((S_ >> b_) & 1)) {                                         \
            K_ |= (u64)1 << b_;                                            \
            S_ |= bcast64(BND, b_);                                        \
          }                                                                \
        }                                                                  \
      }                                                                    \
      int kc_ = (int)__popcll(K_);                                         \
      bool mine_ = (K_ >> lane) & 1;                                       \
      if (mine_) {                                                         \
        int pos_ = out + (int)__popcll(K_ & (((u64)1 << lane) - 1));       \
        if (pos_ < maxp) sel[pos_] = (c) * 64 + lane;                      \
      }                                                                    \
      out += kc_;                                                          \
      if (kc_ > 0 && out < maxp) {                                         \
        int lim_ = mine_ ? ((RC) < FSLOTS ? (RC) : FSLOTS) : 0;            \
        APPLYJ((LA).x, 0)  APPLYJ((LA).y, 1)                               \
        APPLYJ((LA).z, 2)  APPLYJ((LA).w, 3)                               \
        APPLYJ((LB).x, 4)  APPLYJ((LB).y, 5)                               \
        APPLYJ((LB).z, 6)  APPLYJ((LB).w, 7)                               \
        APPLYJ((LC).x, 8)  APPLYJ((LC).y, 9)                               \
        APPLYJ((LC).z, 10) APPLYJ((LC).w, 11)                              \
        APPLYJ((LD).x, 12) APPLYJ((LD).y, 13)                              \
        APPLYJ((LD).z, 14) APPLYJ((LD).w, 15)                              \
        u64 ovf_ = __ballot(mine_ && (RC) > FSLOTS);                       \
        while (ovf_) {                                                     \
          int l_ = (int)__builtin_ctzll(ovf_);                             \
          ovf_ &= ovf_ - 1;                                                \
          int r_ = (c) * 64 + l_;                                          \
          u64 v0_ = M[(size_t)r_ * nw + 2 * lane];                         \
          u64 v1_ = M[(size_t)r_ * nw + 2 * lane + 1];                     \
          live[2 * lane] &= ~v0_;                                          \
          live[2 * lane + 1] &= ~v1_;                                      \
        }                                                                  \
      }                                                                    \
    }                                                                      \
    {                                                                      \
      int cc_ = (c) + 4;                                                   \
      if (cc_ < nch) {                                                     \
        int r_ = cc_ * 64 + lane;                                          \
        int rr_ = r_ < n ? r_ : n - 1;                                     \
        BND = D1[rr_];                                                     \
        RC = rowcnt[rr_];                                                  \
        const int4* lp_ = (const int4*)(rowlist + (size_t)rr_ * FSLOTS);   \
        LA = lp_[0]; LB = lp_[1]; LC = lp_[2]; LD = lp_[3];                \
      }                                                                    \
    }                                                                      \
  }

#define PREF(cc, BND, RC, LA, LB, LC, LD)                                  \
  if ((cc) < nch) {                                                        \
    int r_ = (cc) * 64 + lane;                                             \
    int rr_ = r_ < n ? r_ : n - 1;                                         \
    BND = D1[rr_];                                                         \
    RC = rowcnt[rr_];                                                      \
    const int4* lp_ = (const int4*)(rowlist + (size_t)rr_ * FSLOTS);       \
    LA = lp_[0]; LB = lp_[1]; LC = lp_[2]; LD = lp_[3];                    \
  }

// ---------------- K3: single-wave bulk greedy scan, sparse apply ----------------
__global__ __launch_bounds__(64, 1)
void k_scan(const u64* __restrict__ M, const u64* __restrict__ D1,
            const int* __restrict__ rowcnt, const int* __restrict__ rowlist,
            int n, int nw, int maxp,
            int* __restrict__ sel, int* __restrict__ cnt) {
  __shared__ u64 live[128];
  int lane = threadIdx.x;       // 0..63 (one wave)
  int nch = nw;                 // one 64-box word per chunk

  for (int w = lane; w < 128; w += 64) {
    u64 m = 0;
    if (w < nw) {
      long long hi = (long long)(w + 1) * 64;
      m = (hi <= n) ? ~0ULL
                    : ((n > (long long)w * 64)
                           ? (((u64)1 << (n - w * 64)) - 1) : 0ULL);
    }
    live[w] = m;
  }
  // single wave: LDS ops are in-order, no barrier needed

  // 4-deep ring: diag band + sparse row data for chunks c..c+3
  u64 b0 = 0, b1 = 0, b2 = 0, b3 = 0;
  int rc0 = 0, rc1 = 0, rc2 = 0, rc3 = 0;
  int4 l00 = {0,0,0,0}, l01 = {0,0,0,0}, l02 = {0,0,0,0}, l03 = {0,0,0,0};
  int4 l10 = {0,0,0,0}, l11 = {0,0,0,0}, l12 = {0,0,0,0}, l13 = {0,0,0,0};
  int4 l20 = {0,0,0,0}, l21 = {0,0,0,0}, l22 = {0,0,0,0}, l23 = {0,0,0,0};
  int4 l30 = {0,0,0,0}, l31 = {0,0,0,0}, l32 = {0,0,0,0}, l33 = {0,0,0,0};
  PREF(0, b0, rc0, l00, l01, l02, l03)
  PREF(1, b1, rc1, l10, l11, l12, l13)
  PREF(2, b2, rc2, l20, l21, l22, l23)
  PREF(3, b3, rc3, l30, l31, l32, l33)

  int out = 0;

  for (int kk = 0; kk < nch && out < maxp; kk += 4) {
    CHUNK(kk + 0, b0, rc0, l00, l01, l02, l03)
    CHUNK(kk + 1, b1, rc1, l10, l11, l12, l13)
    CHUNK(kk + 2, b2, rc2, l20, l21, l22, l23)
    CHUNK(kk + 3, b3, rc3, l30, l31, l32, l33)
  }
  if (lane == 0) *cnt = (out < maxp) ? out : maxp;
}

// ---------------- K4: gather outputs ----------------
__global__ void k_emit(const float* __restrict__ preds,
                       const int* __restrict__ sidx,
                       const int* __restrict__ sel,
                       const int* __restrict__ cnt,
                       int maxp, float* __restrict__ out) {
  int k = blockIdx.x * blockDim.x + threadIdx.x;
  if (k >= maxp) return;
  int nk = *cnt;
  if (k < nk) {
    int p = sel[k];
    int orig = sidx[p];
#pragma unroll
    for (int q = 0; q < 5; ++q) out[k * 5 + q] = preds[orig * 5 + q];
    out[(size_t)maxp * 5 + k] = (float)orig;
  } else {
#pragma unroll
    for (int q = 0; q < 5; ++q) out[k * 5 + q] = 0.0f;
    out[(size_t)maxp * 5 + k] = -1.0f;
  }
}

extern "C" void kernel_launch(void* const* d_in, const int* in_sizes, int n_in,
                              void* d_out, int out_size, void* d_ws, size_t ws_size,
                              hipStream_t stream) {
  const float* preds = (const float*)d_in[0];
  const float* thr   = (const float*)d_in[1];
  float* out = (float*)d_out;
  int n    = in_sizes[0] / 5;          // 8192
  int maxp = out_size / 6;             // 1000
  int nw   = (n + 63) / 64;            // 128
  int cpb  = 1024;
  int nyb  = (n + cpb - 1) / cpb;      // 8

  char* ws = (char*)d_ws;
  u64* M = (u64*)ws;
  size_t off = (size_t)n * nw * sizeof(u64);                   // 8 MB
  u64* D1 = (u64*)(ws + off);  off += (size_t)n * sizeof(u64); // 64 KB
  float* sboxes = (float*)(ws + off);  off += (size_t)n * 4 * sizeof(float);
  int*   sidx   = (int*)(ws + off);    off += (size_t)n * sizeof(int);
  int*   sel    = (int*)(ws + off);    off += (size_t)maxp * sizeof(int);
  int*   cnt    = (int*)(ws + off);    off += sizeof(int) * 4;
  int*   rowcnt = (int*)(ws + off);    off += (size_t)n * sizeof(int);
  int*   rowlist= (int*)(ws + off);    off += (size_t)n * FSLOTS * sizeof(int);
  int*   pc     = (int*)(ws + off);    // nyb * n ints

  hipLaunchKernelGGL(k_rank_part, dim3((n + 255) / 256, nyb), dim3(256), 0,
                     stream, preds, n, cpb, pc);
  hipLaunchKernelGGL(k_scatter, dim3((n + 255) / 256), dim3(256), 0, stream,
                     preds, pc, n, nyb, sboxes, sidx, rowcnt);
  hipLaunchKernelGGL(k_mask, dim3(nw, nw), dim3(64), 0, stream,
                     sboxes, n, thr, M, D1, rowcnt, rowlist, nw);
  hipLaunchKernelGGL(k_scan, dim3(1), dim3(64), 0, stream,
                     M, D1, rowcnt, rowlist, n, nw, maxp, sel, cnt);
  hipLaunchKernelGGL(k_emit, dim3((maxp + 255) / 256), dim3(256), 0, stream,
                     preds, sidx, sel, cnt, maxp, out);
}

// Round 22
// 75.610 us; speedup vs baseline: 2.5148x; 1.3105x over previous
//
#include <hip/hip_runtime.h>

typedef unsigned long long u64;

#define FSLOTS 16   // per-row sparse column slots (avg set bits ~4)
#define RCUT 2048   // speculative scan prefix (keep-rate ~95% -> done by ~1050)

// ---------------- K1a: partial rank counts (no atomics) ----------------
__global__ __launch_bounds__(256)
void k_rank_part(const float* __restrict__ preds, int n, int cpb,
                 int* __restrict__ pc) {
  __shared__ float cs[1024];
  int c0 = blockIdx.y * cpb;
  int cn = min(cpb, n - c0);
  for (int j = threadIdx.x; j < cn; j += blockDim.x)
    cs[j] = preds[(c0 + j) * 5 + 4];
  __syncthreads();
  int i = blockIdx.x * blockDim.x + threadIdx.x;
  if (i >= n) return;
  float ci = preds[i * 5 + 4];
  int cnt = 0;
  const float4* cs4 = (const float4*)cs;
  int cn4 = cn >> 2;
  for (int j4 = 0; j4 < cn4; ++j4) {
    float4 c4 = cs4[j4];
    int jb = c0 + j4 * 4;
    cnt += (c4.x > ci) || (c4.x == ci && (jb + 0) < i);
    cnt += (c4.y > ci) || (c4.y == ci && (jb + 1) < i);
    cnt += (c4.z > ci) || (c4.z == ci && (jb + 2) < i);
    cnt += (c4.w > ci) || (c4.w == ci && (jb + 3) < i);
  }
  for (int j = cn4 * 4; j < cn; ++j)
    cnt += (cs[j] > ci) || (cs[j] == ci && (c0 + j) < i);
  pc[(size_t)blockIdx.y * n + i] = cnt;
}

// ---------------- K1b: sum partials + scatter (+ rowcnt zeroing) ----------------
__global__ __launch_bounds__(256)
void k_scatter(const float* __restrict__ preds, const int* __restrict__ pc,
               int n, int nyb, float* __restrict__ sboxes,
               int* __restrict__ sidx, int* __restrict__ rowcnt) {
  int i = blockIdx.x * blockDim.x + threadIdx.x;
  if (i >= n) return;
  rowcnt[i] = 0;
  int pos = 0;
  for (int y = 0; y < nyb; ++y) pos += pc[(size_t)y * n + i];
  sboxes[pos * 4 + 0] = preds[i * 5 + 0];
  sboxes[pos * 4 + 1] = preds[i * 5 + 1];
  sboxes[pos * 4 + 2] = preds[i * 5 + 2];
  sboxes[pos * 4 + 3] = preds[i * 5 + 3];
  sidx[pos] = i;
}

// ---------------- K2: suppression bitmask + SPARSE column lists ----------------
// MODE 0 (lo): only tiles with wx<Rw && ry<Rw (the speculative corner).
// MODE 1 (hi): the rest of the upper triangle; early-exit if *done.
__global__ void k_mask(const float* __restrict__ sboxes, int n,
                       const float* __restrict__ thr_p,
                       u64* __restrict__ M, u64* __restrict__ D1,
                       int* __restrict__ rowcnt, int* __restrict__ rowlist,
                       int nw, int Rw, int mode, const int* __restrict__ done) {
  int wx = blockIdx.x;  // column word
  int ry = blockIdx.y;  // row group
  if (wx < ry) return;
  if (mode == 1) {
    if (wx < Rw && ry < Rw) return;   // covered by lo
    if (*done) return;                // speculation succeeded
  }
  int lane = threadIdx.x;

  __shared__ float4 cb[64];
  __shared__ float cbar[64];
  const float4* sb4 = (const float4*)sboxes;
  int col0 = wx * 64;
  int cj = col0 + lane;
  int cjc = cj < n ? cj : n - 1;
  {
    float4 b4 = sb4[cjc];
    cb[lane] = b4;
    cbar[lane] = __fmul_rn(__fsub_rn(b4.z, b4.x), __fsub_rn(b4.w, b4.y));
  }
  __syncthreads();

  int row = ry * 64 + lane;
  if (row >= n) return;
  float th = *thr_p;
  float4 r4 = sb4[row];
  float rarea = __fmul_rn(__fsub_rn(r4.z, r4.x), __fsub_rn(r4.w, r4.y));

  u64 w = 0;
#pragma unroll 8
  for (int j = 0; j < 64; ++j) {
    float4 c4 = cb[j];
    float ix1 = fmaxf(r4.x, c4.x);
    float iy1 = fmaxf(r4.y, c4.y);
    float ix2 = fminf(r4.z, c4.z);
    float iy2 = fminf(r4.w, c4.w);
    float iw = fmaxf(__fsub_rn(ix2, ix1), 0.0f);
    float ih = fmaxf(__fsub_rn(iy2, iy1), 0.0f);
    float inter = __fmul_rn(iw, ih);
    float denom = __fadd_rn(__fsub_rn(__fadd_rn(rarea, cbar[j]), inter), 1e-12f);
    float iou = __fdiv_rn(inter, denom);
    int col = col0 + j;
    bool sup = (col > row) && (col < n) && (iou > th);
    w |= ((u64)sup) << j;
  }
  M[(size_t)row * nw + wx] = w;
  if (wx == ry) D1[row] = w;
  u64 w2 = w;
  while (w2) {
    int j = (int)__builtin_ctzll(w2);
    w2 &= w2 - 1;
    int idx = atomicAdd(&rowcnt[row], 1);
    if (idx < FSLOTS) rowlist[(size_t)row * FSLOTS + idx] = col0 + j;
  }
}

// wave-uniform 64-bit broadcast from SGPR lane index b
__device__ __forceinline__ u64 bcast64(u64 v, int b) {
  unsigned lo = __builtin_amdgcn_readlane((unsigned)v, b);
  unsigned hi = __builtin_amdgcn_readlane((unsigned)(v >> 32), b);
  return ((u64)hi << 32) | lo;
}

// force a wave-uniform 64-bit value into scalar registers
__device__ __forceinline__ u64 sgpr64(u64 v) {
  unsigned lo = __builtin_amdgcn_readfirstlane((unsigned)v);
  unsigned hi = __builtin_amdgcn_readfirstlane((unsigned)(v >> 32));
  return ((u64)hi << 32) | lo;
}

// 64-lane OR butterfly (6 dependent shfl_xor steps)
__device__ __forceinline__ u64 wor64(u64 v) {
#pragma unroll
  for (int off = 32; off; off >>= 1)
    v |= __shfl_xor(v, off, 64);
  return v;
}

#define APPLYJ(JV, T)                                                      \
  if ((T) < lim_) {                                                        \
    int j_ = (JV);                                                         \
    atomicAnd(&live[j_ >> 6], ~((u64)1 << (j_ & 63)));                     \
  }

#define CHUNK(c, BND, RC, LA, LB, LC, LD)                                  \
  if (out < maxp && (c) < nch) {                                           \
    u64 rem_ = sgpr64(live[(c)]);                                          \
    if (rem_) {                                                            \
      u64 K_;                                                              \
      u64 my_ = ((rem_ >> lane) & 1) ? (BND) : 0;                          \
      u64 A_ = sgpr64(wor64(my_));                                         \
      u64 hot_ = rem_ & A_;                                                \
      if (!hot_) {                                                         \
        K_ = rem_;                                                         \
      } else {                                                             \
        u64 defK_ = rem_ & ~A_;                                            \
        u64 myk_ = ((defK_ >> lane) & 1) ? (BND) : 0;                      \
        u64 S_ = sgpr64(wor64(myk_));                                      \
        K_ = defK_;                                                        \
        while (hot_) {                                                     \
          int b_ = __builtin_amdgcn_readfirstlane(                         \
              (int)__builtin_ctzll(hot_));                                 \
          hot_ &= hot_ - 1;                                                \
          if (!((S_ >> b_) & 1)) {                                         \
            K_ |= (u64)1 << b_;                                            \
            S_ |= bcast64(BND, b_);                                        \
          }                                                                \
        }                                                                  \
      }                                                                    \
      int kc_ = (int)__popcll(K_);                                         \
      bool mine_ = (K_ >> lane) & 1;                                       \
      if (mine_) {                                                         \
        int pos_ = out + (int)__popcll(K_ & (((u64)1 << lane) - 1));       \
        if (pos_ < maxp) sel[pos_] = (c) * 64 + lane;                      \
      }                                                                    \
      out += kc_;                                                          \
      if (kc_ > 0 && out < maxp) {                                         \
        int lim_ = mine_ ? ((RC) < FSLOTS ? (RC) : FSLOTS) : 0;            \
        APPLYJ((LA).x, 0)  APPLYJ((LA).y, 1)                               \
        APPLYJ((LA).z, 2)  APPLYJ((LA).w, 3)                               \
        APPLYJ((LB).x, 4)  APPLYJ((LB).y, 5)                               \
        APPLYJ((LB).z, 6)  APPLYJ((LB).w, 7)                               \
        APPLYJ((LC).x, 8)  APPLYJ((LC).y, 9)                               \
        APPLYJ((LC).z, 10) APPLYJ((LC).w, 11)                              \
        APPLYJ((LD).x, 12) APPLYJ((LD).y, 13)                              \
        APPLYJ((LD).z, 14) APPLYJ((LD).w, 15)                              \
        u64 ovf_ = __ballot(mine_ && (RC) > FSLOTS);                       \
        while (ovf_) {                                                     \
          int l_ = (int)__builtin_ctzll(ovf_);                             \
          ovf_ &= ovf_ - 1;                                                \
          int r_ = (c) * 64 + l_;                                          \
          u64 v0_ = (2 * lane < nch)                                       \
                        ? M[(size_t)r_ * nw + 2 * lane] : 0ULL;            \
          u64 v1_ = (2 * lane + 1 < nch)                                   \
                        ? M[(size_t)r_ * nw + 2 * lane + 1] : 0ULL;        \
          live[2 * lane] &= ~v0_;                                          \
          live[2 * lane + 1] &= ~v1_;                                      \
        }                                                                  \
      }                                                                    \
    }                                                                      \
    {                                                                      \
      int cc_ = (c) + 4;                                                   \
      if (cc_ < nch) {                                                     \
        int r_ = cc_ * 64 + lane;                                          \
        int rr_ = r_ < n ? r_ : n - 1;                                     \
        BND = D1[rr_];                                                     \
        RC = rowcnt[rr_];                                                  \
        const int4* lp_ = (const int4*)(rowlist + (size_t)rr_ * FSLOTS);   \
        LA = lp_[0]; LB = lp_[1]; LC = lp_[2]; LD = lp_[3];                \
      }                                                                    \
    }                                                                      \
  }

#define PREF(cc, BND, RC, LA, LB, LC, LD)                                  \
  if ((cc) < nch) {                                                        \
    int r_ = (cc) * 64 + lane;                                             \
    int rr_ = r_ < n ? r_ : n - 1;                                         \
    BND = D1[rr_];                                                         \
    RC = rowcnt[rr_];                                                      \
    const int4* lp_ = (const int4*)(rowlist + (size_t)rr_ * FSLOTS);       \
    LA = lp_[0]; LB = lp_[1]; LC = lp_[2]; LD = lp_[3];                    \
  }

// ---------------- K3: single-wave bulk greedy scan ----------------
// mode 0 (try): scan chunks < nch_lim; done=1 iff maxp reached or prefix==n.
// mode 1 (full): exit if *done; else rescan with complete data.
__global__ __launch_bounds__(64, 1)
void k_scan(const u64* __restrict__ M, const u64* __restrict__ D1,
            const int* __restrict__ rowcnt, const int* __restrict__ rowlist,
            int n, int nw, int maxp, int nch_lim, int mode,
            int* __restrict__ done,
            int* __restrict__ sel, int* __restrict__ cnt) {
  if (mode == 1 && *done) return;
  __shared__ u64 live[128];
  int lane = threadIdx.x;       // 0..63 (one wave)
  int nch = nch_lim;            // chunks to scan

  for (int w = lane; w < 128; w += 64) {
    u64 m = 0;
    if (w < nw) {
      long long hi = (long long)(w + 1) * 64;
      m = (hi <= n) ? ~0ULL
                    : ((n > (long long)w * 64)
                           ? (((u64)1 << (n - w * 64)) - 1) : 0ULL);
    }
    live[w] = m;
  }

  u64 b0 = 0, b1 = 0, b2 = 0, b3 = 0;
  int rc0 = 0, rc1 = 0, rc2 = 0, rc3 = 0;
  int4 l00 = {0,0,0,0}, l01 = {0,0,0,0}, l02 = {0,0,0,0}, l03 = {0,0,0,0};
  int4 l10 = {0,0,0,0}, l11 = {0,0,0,0}, l12 = {0,0,0,0}, l13 = {0,0,0,0};
  int4 l20 = {0,0,0,0}, l21 = {0,0,0,0}, l22 = {0,0,0,0}, l23 = {0,0,0,0};
  int4 l30 = {0,0,0,0}, l31 = {0,0,0,0}, l32 = {0,0,0,0}, l33 = {0,0,0,0};
  PREF(0, b0, rc0, l00, l01, l02, l03)
  PREF(1, b1, rc1, l10, l11, l12, l13)
  PREF(2, b2, rc2, l20, l21, l22, l23)
  PREF(3, b3, rc3, l30, l31, l32, l33)

  int out = 0;

  for (int kk = 0; kk < nch && out < maxp; kk += 4) {
    CHUNK(kk + 0, b0, rc0, l00, l01, l02, l03)
    CHUNK(kk + 1, b1, rc1, l10, l11, l12, l13)
    CHUNK(kk + 2, b2, rc2, l20, l21, l22, l23)
    CHUNK(kk + 3, b3, rc3, l30, l31, l32, l33)
  }
  if (lane == 0) {
    *cnt = (out < maxp) ? out : maxp;
    if (mode == 0) *done = (out >= maxp || nch_lim >= nw) ? 1 : 0;
  }
}

// ---------------- K4: gather outputs ----------------
__global__ void k_emit(const float* __restrict__ preds,
                       const int* __restrict__ sidx,
                       const int* __restrict__ sel,
                       const int* __restrict__ cnt,
                       int maxp, float* __restrict__ out) {
  int k = blockIdx.x * blockDim.x + threadIdx.x;
  if (k >= maxp) return;
  int nk = *cnt;
  if (k < nk) {
    int p = sel[k];
    int orig = sidx[p];
#pragma unroll
    for (int q = 0; q < 5; ++q) out[k * 5 + q] = preds[orig * 5 + q];
    out[(size_t)maxp * 5 + k] = (float)orig;
  } else {
#pragma unroll
    for (int q = 0; q < 5; ++q) out[k * 5 + q] = 0.0f;
    out[(size_t)maxp * 5 + k] = -1.0f;
  }
}

extern "C" void kernel_launch(void* const* d_in, const int* in_sizes, int n_in,
                              void* d_out, int out_size, void* d_ws, size_t ws_size,
                              hipStream_t stream) {
  const float* preds = (const float*)d_in[0];
  const float* thr   = (const float*)d_in[1];
  float* out = (float*)d_out;
  int n    = in_sizes[0] / 5;          // 8192
  int maxp = out_size / 6;             // 1000
  int nw   = (n + 63) / 64;            // 128
  int Rw   = (RCUT / 64 < nw) ? RCUT / 64 : nw;   // 32
  int cpb  = 1024;
  int nyb  = (n + cpb - 1) / cpb;      // 8

  char* ws = (char*)d_ws;
  u64* M = (u64*)ws;
  size_t off = (size_t)n * nw * sizeof(u64);                   // 8 MB
  u64* D1 = (u64*)(ws + off);  off += (size_t)n * sizeof(u64); // 64 KB
  float* sboxes = (float*)(ws + off);  off += (size_t)n * 4 * sizeof(float);
  int*   sidx   = (int*)(ws + off);    off += (size_t)n * sizeof(int);
  int*   sel    = (int*)(ws + off);    off += (size_t)maxp * sizeof(int);
  int*   cnt    = (int*)(ws + off);    off += sizeof(int) * 4;
  int*   done   = (int*)(ws + off);    off += sizeof(int) * 4;
  int*   rowcnt = (int*)(ws + off);    off += (size_t)n * sizeof(int);
  int*   rowlist= (int*)(ws + off);    off += (size_t)n * FSLOTS * sizeof(int);
  int*   pc     = (int*)(ws + off);    // nyb * n ints

  hipLaunchKernelGGL(k_rank_part, dim3((n + 255) / 256, nyb), dim3(256), 0,
                     stream, preds, n, cpb, pc);
  hipLaunchKernelGGL(k_scatter, dim3((n + 255) / 256), dim3(256), 0, stream,
                     preds, pc, n, nyb, sboxes, sidx, rowcnt);
  // lo corner (speculative)
  hipLaunchKernelGGL(k_mask, dim3(Rw, Rw), dim3(64), 0, stream,
                     sboxes, n, thr, M, D1, rowcnt, rowlist, nw, Rw, 0, done);
  // try-scan of the prefix; writes done
  hipLaunchKernelGGL(k_scan, dim3(1), dim3(64), 0, stream,
                     M, D1, rowcnt, rowlist, n, nw, maxp, Rw, 0, done, sel, cnt);
  // rest of the triangle (skipped when done)
  hipLaunchKernelGGL(k_mask, dim3(nw, nw), dim3(64), 0, stream,
                     sboxes, n, thr, M, D1, rowcnt, rowlist, nw, Rw, 1, done);
  // full rescan (skipped when done)
  hipLaunchKernelGGL(k_scan, dim3(1), dim3(64), 0, stream,
                     M, D1, rowcnt, rowlist, n, nw, maxp, nw, 1, done, sel, cnt);
  hipLaunchKernelGGL(k_emit, dim3((maxp + 255) / 256), dim3(256), 0, stream,
                     preds, sidx, sel, cnt, maxp, out);
}

// Round 23
// 74.492 us; speedup vs baseline: 2.5526x; 1.0150x over previous
//
#include <hip/hip_runtime.h>

typedef unsigned long long u64;

#define FSLOTS 16   // per-row sparse column slots (avg set bits ~4)
#define RCUT 2048   // speculative scan prefix

// ---------------- K1a: partial rank counts (no atomics) ----------------
__global__ __launch_bounds__(256)
void k_rank_part(const float* __restrict__ preds, int n, int cpb,
                 int* __restrict__ pc) {
  __shared__ float cs[1024];
  int c0 = blockIdx.y * cpb;
  int cn = min(cpb, n - c0);
  for (int j = threadIdx.x; j < cn; j += blockDim.x)
    cs[j] = preds[(c0 + j) * 5 + 4];
  __syncthreads();
  int i = blockIdx.x * blockDim.x + threadIdx.x;
  if (i >= n) return;
  float ci = preds[i * 5 + 4];
  int cnt = 0;
  const float4* cs4 = (const float4*)cs;
  int cn4 = cn >> 2;
  for (int j4 = 0; j4 < cn4; ++j4) {
    float4 c4 = cs4[j4];
    int jb = c0 + j4 * 4;
    cnt += (c4.x > ci) || (c4.x == ci && (jb + 0) < i);
    cnt += (c4.y > ci) || (c4.y == ci && (jb + 1) < i);
    cnt += (c4.z > ci) || (c4.z == ci && (jb + 2) < i);
    cnt += (c4.w > ci) || (c4.w == ci && (jb + 3) < i);
  }
  for (int j = cn4 * 4; j < cn; ++j)
    cnt += (cs[j] > ci) || (cs[j] == ci && (c0 + j) < i);
  pc[(size_t)blockIdx.y * n + i] = cnt;
}

// ---------------- K1b: sum partials + scatter (+ rowcnt zeroing) ----------------
__global__ __launch_bounds__(256)
void k_scatter(const float* __restrict__ preds, const int* __restrict__ pc,
               int n, int nyb, float* __restrict__ sboxes,
               int* __restrict__ sidx, int* __restrict__ rowcnt) {
  int i = blockIdx.x * blockDim.x + threadIdx.x;
  if (i >= n) return;
  rowcnt[i] = 0;
  int pos = 0;
  for (int y = 0; y < nyb; ++y) pos += pc[(size_t)y * n + i];
  sboxes[pos * 4 + 0] = preds[i * 5 + 0];
  sboxes[pos * 4 + 1] = preds[i * 5 + 1];
  sboxes[pos * 4 + 2] = preds[i * 5 + 2];
  sboxes[pos * 4 + 3] = preds[i * 5 + 3];
  sidx[pos] = i;
}

// ---------------- K2: suppression bitmask + SPARSE column lists ----------------
// mode 0 (lo): 2D grid over the Rw x Rw speculative corner.
// mode 1 (hi): 1D PACKED grid over upper-tri tiles with wx >= Rw (exact
//              count, no null blocks); early-exit when *done.
__global__ void k_mask(const float* __restrict__ sboxes, int n,
                       const float* __restrict__ thr_p,
                       u64* __restrict__ M, u64* __restrict__ D1,
                       int* __restrict__ rowcnt, int* __restrict__ rowlist,
                       int nw, int Rw, int mode, const int* __restrict__ done) {
  int wx, ry;
  if (mode == 0) {
    wx = blockIdx.x; ry = blockIdx.y;
    if (wx < ry) return;
  } else {
    if (*done) return;
    int u = blockIdx.x + (Rw * (Rw + 1)) / 2;   // tri index, wx >= Rw
    int w = (int)((sqrt(8.0 * u + 1.0) - 1.0) * 0.5);
    while ((w + 1) * (w + 2) / 2 <= u) ++w;
    while (w * (w + 1) / 2 > u) --w;
    wx = w; ry = u - w * (w + 1) / 2;
  }
  int lane = threadIdx.x;

  __shared__ float4 cb[64];
  __shared__ float cbar[64];
  const float4* sb4 = (const float4*)sboxes;
  int col0 = wx * 64;
  int cj = col0 + lane;
  int cjc = cj < n ? cj : n - 1;
  {
    float4 b4 = sb4[cjc];
    cb[lane] = b4;
    cbar[lane] = __fmul_rn(__fsub_rn(b4.z, b4.x), __fsub_rn(b4.w, b4.y));
  }
  __syncthreads();

  int row = ry * 64 + lane;
  if (row >= n) return;
  float th = *thr_p;
  float4 r4 = sb4[row];
  float rarea = __fmul_rn(__fsub_rn(r4.z, r4.x), __fsub_rn(r4.w, r4.y));

  u64 w = 0;
#pragma unroll 8
  for (int j = 0; j < 64; ++j) {
    float4 c4 = cb[j];
    float ix1 = fmaxf(r4.x, c4.x);
    float iy1 = fmaxf(r4.y, c4.y);
    float ix2 = fminf(r4.z, c4.z);
    float iy2 = fminf(r4.w, c4.w);
    float iw = fmaxf(__fsub_rn(ix2, ix1), 0.0f);
    float ih = fmaxf(__fsub_rn(iy2, iy1), 0.0f);
    float inter = __fmul_rn(iw, ih);
    float denom = __fadd_rn(__fsub_rn(__fadd_rn(rarea, cbar[j]), inter), 1e-12f);
    float iou = __fdiv_rn(inter, denom);
    int col = col0 + j;
    bool sup = (col > row) && (col < n) && (iou > th);
    w |= ((u64)sup) << j;
  }
  M[(size_t)row * nw + wx] = w;
  if (wx == ry) D1[row] = w;
  int pcw = (int)__popcll(w);
  if (pcw) {
    int base = atomicAdd(&rowcnt[row], pcw);
    u64 w2 = w;
    int k = 0;
    while (w2) {
      int j = (int)__builtin_ctzll(w2);
      w2 &= w2 - 1;
      int idx = base + k;
      if (idx < FSLOTS) rowlist[(size_t)row * FSLOTS + idx] = col0 + j;
      ++k;
    }
  }
}

// wave-uniform 64-bit broadcast from SGPR lane index b
__device__ __forceinline__ u64 bcast64(u64 v, int b) {
  unsigned lo = __builtin_amdgcn_readlane((unsigned)v, b);
  unsigned hi = __builtin_amdgcn_readlane((unsigned)(v >> 32), b);
  return ((u64)hi << 32) | lo;
}

// force a wave-uniform 64-bit value into scalar registers
__device__ __forceinline__ u64 sgpr64(u64 v) {
  unsigned lo = __builtin_amdgcn_readfirstlane((unsigned)v);
  unsigned hi = __builtin_amdgcn_readfirstlane((unsigned)(v >> 32));
  return ((u64)hi << 32) | lo;
}

// 64-lane OR butterfly (6 dependent shfl_xor steps)
__device__ __forceinline__ u64 wor64(u64 v) {
#pragma unroll
  for (int off = 32; off; off >>= 1)
    v |= __shfl_xor(v, off, 64);
  return v;
}

#define APPLYJ(JV, T)                                                      \
  if ((T) < lim_) {                                                        \
    int j_ = (JV);                                                         \
    atomicAnd(&live[j_ >> 6], ~((u64)1 << (j_ & 63)));                     \
  }

#define CHUNK(c, BND, RC, LA, LB, LC, LD)                                  \
  if (out < maxp && (c) < nch) {                                           \
    u64 rem_ = sgpr64(live[(c)]);                                          \
    if (rem_) {                                                            \
      u64 K_;                                                              \
      u64 my_ = ((rem_ >> lane) & 1) ? (BND) : 0;                          \
      u64 A_ = sgpr64(wor64(my_));                                         \
      u64 hot_ = rem_ & A_;                                                \
      if (!hot_) {                                                         \
        K_ = rem_;                                                         \
      } else {                                                             \
        u64 defK_ = rem_ & ~A_;                                            \
        u64 myk_ = ((defK_ >> lane) & 1) ? (BND) : 0;                      \
        u64 S_ = sgpr64(wor64(myk_));                                      \
        K_ = defK_;                                                        \
        while (hot_) {                                                     \
          int b_ = __builtin_amdgcn_readfirstlane(                         \
              (int)__builtin_ctzll(hot_));                                 \
          hot_ &= hot_ - 1;                                                \
          if (!((S_ >> b_) & 1)) {                                         \
            K_ |= (u64)1 << b_;                                            \
            S_ |= bcast64(BND, b_);                                        \
          }                                                                \
        }                                                                  \
      }                                                                    \
      int kc_ = (int)__popcll(K_);                                         \
      bool mine_ = (K_ >> lane) & 1;                                       \
      if (mine_) {                                                         \
        int pos_ = out + (int)__popcll(K_ & (((u64)1 << lane) - 1));       \
        if (pos_ < maxp) sel[pos_] = (c) * 64 + lane;                      \
      }                                                                    \
      out += kc_;                                                          \
      if (kc_ > 0 && out < maxp) {                                         \
        int lim_ = mine_ ? ((RC) < FSLOTS ? (RC) : FSLOTS) : 0;            \
        APPLYJ((LA).x, 0)  APPLYJ((LA).y, 1)                               \
        APPLYJ((LA).z, 2)  APPLYJ((LA).w, 3)                               \
        APPLYJ((LB).x, 4)  APPLYJ((LB).y, 5)                               \
        APPLYJ((LB).z, 6)  APPLYJ((LB).w, 7)                               \
        APPLYJ((LC).x, 8)  APPLYJ((LC).y, 9)                               \
        APPLYJ((LC).z, 10) APPLYJ((LC).w, 11)                              \
        APPLYJ((LD).x, 12) APPLYJ((LD).y, 13)                              \
        APPLYJ((LD).z, 14) APPLYJ((LD).w, 15)                              \
        u64 ovf_ = __ballot(mine_ && (RC) > FSLOTS);                       \
        while (ovf_) {                                                     \
          int l_ = (int)__builtin_ctzll(ovf_);                             \
          ovf_ &= ovf_ - 1;                                                \
          int r_ = (c) * 64 + l_;                                          \
          u64 v0_ = (2 * lane < nch)                                       \
                        ? M[(size_t)r_ * nw + 2 * lane] : 0ULL;            \
          u64 v1_ = (2 * lane + 1 < nch)                                   \
                        ? M[(size_t)r_ * nw + 2 * lane + 1] : 0ULL;        \
          live[2 * lane] &= ~v0_;                                          \
          live[2 * lane + 1] &= ~v1_;                                      \
        }                                                                  \
      }                                                                    \
    }                                                                      \
    {                                                                      \
      int cc_ = (c) + 4;                                                   \
      if (cc_ < nch) {                                                     \
        int r_ = cc_ * 64 + lane;                                          \
        int rr_ = r_ < n ? r_ : n - 1;                                     \
        BND = D1[rr_];                                                     \
        RC = rowcnt[rr_];                                                  \
        const int4* lp_ = (const int4*)(rowlist + (size_t)rr_ * FSLOTS);   \
        LA = lp_[0]; LB = lp_[1]; LC = lp_[2]; LD = lp_[3];                \
      }                                                                    \
    }                                                                      \
  }

#define PREF(cc, BND, RC, LA, LB, LC, LD)                                  \
  if ((cc) < nch) {                                                        \
    int r_ = (cc) * 64 + lane;                                             \
    int rr_ = r_ < n ? r_ : n - 1;                                         \
    BND = D1[rr_];                                                         \
    RC = rowcnt[rr_];                                                      \
    const int4* lp_ = (const int4*)(rowlist + (size_t)rr_ * FSLOTS);       \
    LA = lp_[0]; LB = lp_[1]; LC = lp_[2]; LD = lp_[3];                    \
  }

#define SCAN_BODY(NCH_)                                                    \
  int nch = (NCH_);                                                        \
  for (int w = lane; w < 128; w += 64) {                                   \
    u64 m = 0;                                                             \
    if (w < nw) {                                                          \
      long long hi = (long long)(w + 1) * 64;                              \
      m = (hi <= n) ? ~0ULL                                                \
                    : ((n > (long long)w * 64)                             \
                           ? (((u64)1 << (n - w * 64)) - 1) : 0ULL);       \
    }                                                                      \
    live[w] = m;                                                           \
  }                                                                        \
  u64 b0 = 0, b1 = 0, b2 = 0, b3 = 0;                                      \
  int rc0 = 0, rc1 = 0, rc2 = 0, rc3 = 0;                                  \
  int4 l00 = {0,0,0,0}, l01 = {0,0,0,0}, l02 = {0,0,0,0}, l03 = {0,0,0,0}; \
  int4 l10 = {0,0,0,0}, l11 = {0,0,0,0}, l12 = {0,0,0,0}, l13 = {0,0,0,0}; \
  int4 l20 = {0,0,0,0}, l21 = {0,0,0,0}, l22 = {0,0,0,0}, l23 = {0,0,0,0}; \
  int4 l30 = {0,0,0,0}, l31 = {0,0,0,0}, l32 = {0,0,0,0}, l33 = {0,0,0,0}; \
  PREF(0, b0, rc0, l00, l01, l02, l03)                                     \
  PREF(1, b1, rc1, l10, l11, l12, l13)                                     \
  PREF(2, b2, rc2, l20, l21, l22, l23)                                     \
  PREF(3, b3, rc3, l30, l31, l32, l33)                                     \
  int out = 0;                                                             \
  for (int kk = 0; kk < nch && out < maxp; kk += 4) {                      \
    CHUNK(kk + 0, b0, rc0, l00, l01, l02, l03)                             \
    CHUNK(kk + 1, b1, rc1, l10, l11, l12, l13)                             \
    CHUNK(kk + 2, b2, rc2, l20, l21, l22, l23)                             \
    CHUNK(kk + 3, b3, rc3, l30, l31, l32, l33)                             \
  }

// ---------------- K3: single-wave speculative try-scan ----------------
__global__ __launch_bounds__(64, 1)
void k_scan_try(const u64* __restrict__ M, const u64* __restrict__ D1,
                const int* __restrict__ rowcnt, const int* __restrict__ rowlist,
                int n, int nw, int maxp, int nch_lim,
                int* __restrict__ done,
                int* __restrict__ sel, int* __restrict__ cnt) {
  __shared__ u64 live[128];
  int lane = threadIdx.x;
  SCAN_BODY(nch_lim)
  if (lane == 0) {
    *cnt = (out < maxp) ? out : maxp;
    *done = (out >= maxp || nch_lim >= nw) ? 1 : 0;
  }
}

// ---------------- K5: finish = (cold full rescan) + emit ----------------
__global__ __launch_bounds__(256, 1)
void k_finish(const u64* __restrict__ M, const u64* __restrict__ D1,
              const int* __restrict__ rowcnt, const int* __restrict__ rowlist,
              const float* __restrict__ preds, const int* __restrict__ sidx,
              int n, int nw, int maxp, const int* __restrict__ done,
              int* __restrict__ sel, int* __restrict__ cnt,
              float* __restrict__ outp) {
  __shared__ u64 live[128];
  __shared__ int nk_s;
  int t = threadIdx.x;
  int dn = *done;
  if (!dn) {
    if (t < 64) {     // wave 0: full rescan with complete mask data
      int lane = t;
      SCAN_BODY(nw)
      if (lane == 0) {
        int nk = (out < maxp) ? out : maxp;
        *cnt = nk;
        nk_s = nk;
      }
    }
  } else {
    if (t == 0) nk_s = *cnt;
  }
  __syncthreads();
  int nk = nk_s;
  for (int k = t; k < maxp; k += 256) {
    if (k < nk) {
      int p = sel[k];
      int orig = sidx[p];
#pragma unroll
      for (int q = 0; q < 5; ++q) outp[k * 5 + q] = preds[orig * 5 + q];
      outp[(size_t)maxp * 5 + k] = (float)orig;
    } else {
#pragma unroll
      for (int q = 0; q < 5; ++q) outp[k * 5 + q] = 0.0f;
      outp[(size_t)maxp * 5 + k] = -1.0f;
    }
  }
}

extern "C" void kernel_launch(void* const* d_in, const int* in_sizes, int n_in,
                              void* d_out, int out_size, void* d_ws, size_t ws_size,
                              hipStream_t stream) {
  const float* preds = (const float*)d_in[0];
  const float* thr   = (const float*)d_in[1];
  float* out = (float*)d_out;
  int n    = in_sizes[0] / 5;          // 8192
  int maxp = out_size / 6;             // 1000
  int nw   = (n + 63) / 64;            // 128
  int Rw   = (RCUT / 64 < nw) ? RCUT / 64 : nw;   // 32
  int cpb  = 1024;
  int nyb  = (n + cpb - 1) / cpb;      // 8
  int hiT  = (nw * (nw + 1)) / 2 - (Rw * (Rw + 1)) / 2;   // 7728

  char* ws = (char*)d_ws;
  u64* M = (u64*)ws;
  size_t off = (size_t)n * nw * sizeof(u64);                   // 8 MB
  u64* D1 = (u64*)(ws + off);  off += (size_t)n * sizeof(u64); // 64 KB
  float* sboxes = (float*)(ws + off);  off += (size_t)n * 4 * sizeof(float);
  int*   sidx   = (int*)(ws + off);    off += (size_t)n * sizeof(int);
  int*   sel    = (int*)(ws + off);    off += (size_t)maxp * sizeof(int);
  int*   cnt    = (int*)(ws + off);    off += sizeof(int) * 4;
  int*   done   = (int*)(ws + off);    off += sizeof(int) * 4;
  int*   rowcnt = (int*)(ws + off);    off += (size_t)n * sizeof(int);
  int*   rowlist= (int*)(ws + off);    off += (size_t)n * FSLOTS * sizeof(int);
  int*   pc     = (int*)(ws + off);    // nyb * n ints

  hipLaunchKernelGGL(k_rank_part, dim3((n + 255) / 256, nyb), dim3(256), 0,
                     stream, preds, n, cpb, pc);
  hipLaunchKernelGGL(k_scatter, dim3((n + 255) / 256), dim3(256), 0, stream,
                     preds, pc, n, nyb, sboxes, sidx, rowcnt);
  hipLaunchKernelGGL(k_mask, dim3(Rw, Rw), dim3(64), 0, stream,
                     sboxes, n, thr, M, D1, rowcnt, rowlist, nw, Rw, 0, done);
  hipLaunchKernelGGL(k_scan_try, dim3(1), dim3(64), 0, stream,
                     M, D1, rowcnt, rowlist, n, nw, maxp, Rw, done, sel, cnt);
  if (hiT > 0)
    hipLaunchKernelGGL(k_mask, dim3(hiT), dim3(64), 0, stream,
                       sboxes, n, thr, M, D1, rowcnt, rowlist, nw, Rw, 1, done);
  hipLaunchKernelGGL(k_finish, dim3(1), dim3(256), 0, stream,
                     M, D1, rowcnt, rowlist, preds, sidx, n, nw, maxp, done,
                     sel, cnt, out);
}